// Round 14
// baseline (382.341 us; speedup 1.0000x reference)
//
#include <hip/hip_runtime.h>
#include <hip/hip_bf16.h>

// Problem constants (B=1)
#define S_LEN 2048
#define HID 2048
#define NH 16
#define HD 256
#define NROT 64
#define NOPE 192
#define QL 1024
#define OR_ 512
#define NG 4
#define HPG 4
#define EPS 1e-6f
#define SCALE 0.0625f   // 256^-0.5

typedef __bf16 bf16x8 __attribute__((ext_vector_type(8)));
typedef short s16x8 __attribute__((ext_vector_type(8)));
typedef float f32x4 __attribute__((ext_vector_type(4)));

#define MFMA(a, b, c) __builtin_amdgcn_mfma_f32_16x16x32_bf16( \
    __builtin_bit_cast(bf16x8, a), __builtin_bit_cast(bf16x8, b), c, 0, 0, 0)

__device__ __forceinline__ unsigned short f2bf(float x) {
  unsigned int u = __builtin_bit_cast(unsigned int, x);
  u += 0x7FFFu + ((u >> 16) & 1u);   // RNE
  return (unsigned short)(u >> 16);
}
__device__ __forceinline__ float bf2f(unsigned short b) {
  unsigned int u = ((unsigned int)b) << 16;
  return __builtin_bit_cast(float, u);
}

// async global->LDS 16B: dest must be wave-uniform base + lane*16 (linear LDS)
#define GLD_LDS16(gp, lp) __builtin_amdgcn_global_load_lds( \
    (__attribute__((address_space(1))) void*)(gp), \
    (__attribute__((address_space(3))) void*)(lp), 16, 0, 0)

// ---------------- fp32 -> bf16 convert (single tensor) ----------------
__global__ __launch_bounds__(256) void f32_to_bf16(const float* __restrict__ in,
                                                   unsigned short* __restrict__ out, int n4) {
  int i = blockIdx.x * 256 + threadIdx.x;
  if (i < n4) {
    float4 v = ((const float4*)in)[i];
    ushort4 o;
    o.x = f2bf(v.x); o.y = f2bf(v.y); o.z = f2bf(v.z); o.w = f2bf(v.w);
    ((ushort4*)out)[i] = o;
  }
}

// ---------------- fused convert of the 5 pre-attention tensors ----------------
__global__ __launch_bounds__(256) void conv5(
    const float* __restrict__ x, const float* __restrict__ wqa,
    const float* __restrict__ wqb, const float* __restrict__ wkv,
    const float* __restrict__ woa,
    unsigned short* __restrict__ xo, unsigned short* __restrict__ wqao,
    unsigned short* __restrict__ wqbo, unsigned short* __restrict__ wkvo,
    unsigned short* __restrict__ woao) {
  int i = blockIdx.x * 256 + threadIdx.x;
  const float* src; unsigned short* dst; int off;
  if (i < 1048576)      { src = x;   dst = xo;   off = i; }
  else if (i < 1572864) { src = wqa; dst = wqao; off = i - 1048576; }
  else if (i < 2621440) { src = wqb; dst = wqbo; off = i - 1572864; }
  else if (i < 2752512) { src = wkv; dst = wkvo; off = i - 2621440; }
  else                  { src = woa; dst = woao; off = i - 2752512; }
  float4 v = ((const float4*)src)[off];
  ushort4 o;
  o.x = f2bf(v.x); o.y = f2bf(v.y); o.z = f2bf(v.z); o.w = f2bf(v.w);
  ((ushort4*)dst)[off] = o;
}

// ------------- bf16 MFMA GEMM: C[M,N] = A[M,K] @ B[N,K]^T, tile 128xBN -------
// R10: global_load_lds width-16 staging (m97 pattern). Linear LDS.
// R14: split-K via z-grid (aoffz/boffz = K-advance, coffz = partial stride).
// R15: BN=64 variant for N-narrow GEMMs (2 blocks/CU).
template <int BN>
__global__ __launch_bounds__(256, 2) void gemm_bf16(
    const unsigned short* __restrict__ A, const unsigned short* __restrict__ B,
    void* __restrict__ Cv, int K, int lda, int ldb, int ldc,
    long aoffz, long boffz, long coffz, int store_bf) {
  constexpr int NF = BN / 32;   // n-frags per wave
  __shared__ __align__(16) unsigned short As[128 * 32];
  __shared__ __align__(16) unsigned short Bs[BN * 32];
  A += (size_t)blockIdx.z * aoffz;
  B += (size_t)blockIdx.z * boffz;
  const int tid = threadIdx.x;
  const int wave = tid >> 6, lane = tid & 63;
  const int col = lane & 15, grp = lane >> 4;
  const int wm = wave >> 1, wn = wave & 1;
  const int m0 = blockIdx.y * 128, n0 = blockIdx.x * BN;

  f32x4 acc[4][NF];
#pragma unroll
  for (int i = 0; i < 4; ++i)
#pragma unroll
    for (int j = 0; j < NF; ++j) acc[i][j] = (f32x4){0.f, 0.f, 0.f, 0.f};

  for (int k0 = 0; k0 < K; k0 += 32) {
#pragma unroll
    for (int u = 0; u < 2; ++u) {
      int lin = u * 256 + tid;
      int r = lin >> 2, c8 = (lin & 3) * 8;
      GLD_LDS16(A + (size_t)(m0 + r) * lda + k0 + c8, &As[lin * 8]);
    }
#pragma unroll
    for (int u = 0; u < BN / 64; ++u) {
      int lin = u * 256 + tid;
      int r = lin >> 2, c8 = (lin & 3) * 8;
      GLD_LDS16(B + (size_t)(n0 + r) * ldb + k0 + c8, &Bs[lin * 8]);
    }
    __syncthreads();
    s16x8 a[4], b[NF];
#pragma unroll
    for (int i = 0; i < 4; ++i)
      a[i] = *(const s16x8*)&As[(wm * 64 + i * 16 + col) * 32 + grp * 8];
#pragma unroll
    for (int j = 0; j < NF; ++j)
      b[j] = *(const s16x8*)&Bs[(wn * (BN / 2) + j * 16 + col) * 32 + grp * 8];
#pragma unroll
    for (int i = 0; i < 4; ++i)
#pragma unroll
      for (int j = 0; j < NF; ++j)
        acc[i][j] = MFMA(a[i], b[j], acc[i][j]);
    __syncthreads();
  }

  if (store_bf) {
    unsigned short* C = (unsigned short*)Cv + (size_t)blockIdx.z * coffz;
#pragma unroll
    for (int i = 0; i < 4; ++i)
#pragma unroll
      for (int j = 0; j < NF; ++j)
#pragma unroll
        for (int r = 0; r < 4; ++r)
          C[(size_t)(m0 + wm * 64 + i * 16 + grp * 4 + r) * ldc +
            n0 + wn * (BN / 2) + j * 16 + col] = f2bf(acc[i][j][r]);
  } else {
    float* C = (float*)Cv + (size_t)blockIdx.z * coffz;
#pragma unroll
    for (int i = 0; i < 4; ++i)
#pragma unroll
      for (int j = 0; j < NF; ++j)
#pragma unroll
        for (int r = 0; r < 4; ++r)
          C[(size_t)(m0 + wm * 64 + i * 16 + grp * 4 + r) * ldc +
            n0 + wn * (BN / 2) + j * 16 + col] = acc[i][j][r];
  }
}

// ---------------- split-K combine (2 partials) + RMSNorm -> bf16 ----------------
__global__ __launch_bounds__(256) void rms_combine2(const float* __restrict__ p,
                                                    unsigned short* __restrict__ out,
                                                    const float* __restrict__ w) {
  int row = blockIdx.x;
  const float* r0 = p + (size_t)row * QL;
  const float* r1 = r0 + 2097152;   // second partial (2048*1024 floats)
  __shared__ float buf[QL];
  __shared__ float red[256];
  float s = 0.f;
  for (int i = threadIdx.x; i < QL; i += 256) {
    float v = r0[i] + r1[i];
    buf[i] = v;
    s += v * v;
  }
  red[threadIdx.x] = s;
  __syncthreads();
  for (int off = 128; off > 0; off >>= 1) {
    if (threadIdx.x < off) red[threadIdx.x] += red[threadIdx.x + off];
    __syncthreads();
  }
  float r = rsqrtf(red[0] / (float)QL + EPS);
  for (int i = threadIdx.x; i < QL; i += 256)
    out[(size_t)row * QL + i] = f2bf(buf[i] * r * w[i]);
}

// ------- split-K combine (8 partials) + KV RMS + RoPE -> kv_bf + kvT -------
// R16: kvT is TILED [S/64][HD][64] (chunk-contiguous V^T).
__global__ __launch_bounds__(256) void kv_combine8(const float* __restrict__ p,
                                                   const float* __restrict__ w,
                                                   const float* __restrict__ freqs,
                                                   unsigned short* __restrict__ kv,
                                                   unsigned short* __restrict__ kvT) {
  int s = blockIdx.x;
  int d = threadIdx.x;
  const float* b = p + (size_t)s * HD + d;
  float v = 0.f;
#pragma unroll
  for (int z = 0; z < 8; ++z) v += b[(size_t)z * 524288];   // 2048*256 stride
  __shared__ float red[256];
  __shared__ float sm[256];
  red[d] = v * v;
  __syncthreads();
  for (int off = 128; off > 0; off >>= 1) {
    if (d < off) red[d] += red[d + off];
    __syncthreads();
  }
  float r = rsqrtf(red[0] / 256.0f + EPS);
  float nv = v * r * w[d];
  sm[d] = nv;
  __syncthreads();
  float outv = nv;
  if (d >= NOPE) {
    int j = (d - NOPE) >> 1;
    float f = freqs[(size_t)s * (NROT / 2) + j];
    float c = cosf(f), si = sinf(f);
    float x1 = sm[NOPE + 2 * j], x2 = sm[NOPE + 2 * j + 1];
    outv = ((d & 1) == 0) ? (x1 * c - x2 * si) : (x1 * si + x2 * c);
  }
  unsigned short ov = f2bf(outv);
  kv[(size_t)s * HD + d] = ov;
  kvT[(size_t)(s & ~63) * HD + d * 64 + (s & 63)] = ov;   // tiled V^T
}

// ---------------- MFMA flash attention v6 + fused Q-norm/RoPE (R17; FINAL) ----
// 64-key chunks, register prefetch of all global traffic, balanced CU pairing
// (R11), setprio on MFMA clusters (T5), tiled kvT (R16), fused Q RMS+RoPE (R17).
// R19: PV-pipeline (R18) spilled; R20 KV-split failed correctness. This v6
// structure is the verified local optimum: 4 restructure attempts all lost.
__global__ __launch_bounds__(256, 2) void attn_mfma(
    const unsigned short* __restrict__ qbf,   // (S, NH*HD) bf16 RAW (pre-norm)
    const unsigned short* __restrict__ kvbf,  // (S, HD) bf16
    const unsigned short* __restrict__ kvT,   // tiled [S/64][HD][64] bf16
    const float* __restrict__ sink,
    const float* __restrict__ freqs,
    unsigned short* __restrict__ ob) {        // (S, NH*HD) bf16
  __shared__ __align__(16) unsigned short kv_s[64 * 264];  // [t][d]
  __shared__ __align__(16) unsigned short p_s[64 * 72];    // [row][t] (64 t + 8 pad)
  __shared__ float alpha_s[64];
  __shared__ float inv_s[64];

  const int tid = threadIdx.x;
  const int wave = tid >> 6, lane = tid & 63;
  const int col = lane & 15, grp = lane >> 4;
  // balanced pairing remap: lin in [0,512)
  const int lin = blockIdx.y * gridDim.x + blockIdx.x;
  const int half = lin >> 8, li = lin & 255;
  const int tr = li & 31;
  const int h = (half == 0) ? (li >> 5) : 8 + (li >> 5);
  const int q0 = ((half == 0) ? (31 - tr) : tr) * 64;
  const int qrow = q0 + wave * 16;

  // Q fragments: 8 named s16x8 regs (32 VGPRs)
  const unsigned short* qbase =
      qbf + (size_t)(qrow + col) * (NH * HD) + (size_t)h * HD + grp * 8;
#define QDECL(ko, nam) s16x8 nam = *(const s16x8*)(qbase + (ko) * 32);
  QDECL(0, qf0) QDECL(1, qf1) QDECL(2, qf2) QDECL(3, qf3)
  QDECL(4, qf4) QDECL(5, qf5) QDECL(6, qf6) QDECL(7, qf7)

  // ---- R17 fused Q RMS + RoPE ----
  {
    float sq = 0.f;
#define QSQ(qf) { _Pragma("unroll") \
    for (int j = 0; j < 8; ++j) { float v = bf2f((unsigned short)qf[j]); sq += v * v; } }
    QSQ(qf0) QSQ(qf1) QSQ(qf2) QSQ(qf3) QSQ(qf4) QSQ(qf5) QSQ(qf6) QSQ(qf7)
    sq += __shfl_xor(sq, 16);
    sq += __shfl_xor(sq, 32);
    const float qr_ = rsqrtf(sq * (1.0f / 256.0f) + EPS);
#define QSC(qf) { _Pragma("unroll") \
    for (int j = 0; j < 8; ++j) qf[j] = (short)f2bf(bf2f((unsigned short)qf[j]) * qr_); }
    QSC(qf0) QSC(qf1) QSC(qf2) QSC(qf3) QSC(qf4) QSC(qf5)
    const float* fb = freqs + (size_t)(qrow + col) * (NROT / 2);
#define QSR(qf, jb) { _Pragma("unroll") \
    for (int u = 0; u < 4; ++u) { \
      float f = fb[(jb) + grp * 4 + u]; \
      float c = cosf(f), s = sinf(f); \
      float x1 = bf2f((unsigned short)qf[2 * u]) * qr_; \
      float x2 = bf2f((unsigned short)qf[2 * u + 1]) * qr_; \
      qf[2 * u]     = (short)f2bf(x1 * c - x2 * s); \
      qf[2 * u + 1] = (short)f2bf(x1 * s + x2 * c); } }
    QSR(qf6, 0) QSR(qf7, 16)
  }

  const f32x4 z4 = (f32x4){0.f, 0.f, 0.f, 0.f};
  float m0r = -1e30f, m1r = -1e30f, m2r = -1e30f, m3r = -1e30f;
  float lp0 = 0.f, lp1 = 0.f, lp2 = 0.f, lp3 = 0.f;   // per-lane partial l

#define FOR16(M) M(0,0,o00) M(0,1,o01) M(0,2,o02) M(0,3,o03) \
                 M(1,0,o10) M(1,1,o11) M(1,2,o12) M(1,3,o13) \
                 M(2,0,o20) M(2,1,o21) M(2,2,o22) M(2,3,o23) \
                 M(3,0,o30) M(3,1,o31) M(3,2,o32) M(3,3,o33)
#define DECLO(i, j, onam) f32x4 onam = z4;
  FOR16(DECLO)

  // Staging lane geometry: thread owns rows {tS+8k, k=0..7}, cols [ddS, ddS+8)
  const int tS = tid >> 5, ddS = (tid & 31) * 8;

  // Initial stage of chunk 0
  {
    const unsigned short* sb = kvbf + (size_t)tS * HD + ddS;
#pragma unroll
    for (int k = 0; k < 8; ++k)
      *(s16x8*)&kv_s[(tS + 8 * k) * 264 + ddS] = *(const s16x8*)(sb + (size_t)(8 * k) * HD);
  }

  const int nch = q0 / 64 + 1;
  for (int ch = 0; ch < nch; ++ch) {
    const int t0 = ch * 64;
    __syncthreads();   // kv_s(ch) ready; p_s/alpha_s(ch-1) consumed

    // ---- PREFETCH: next chunk staging (8) + this chunk's vf B-frags (8) ----
    const bool havest = (ch + 1 < nch);
    s16x8 st0 = {}, st1 = {}, st2 = {}, st3 = {}, st4 = {}, st5 = {}, st6 = {}, st7 = {};
    if (havest) {
      const unsigned short* sb = kvbf + (size_t)(t0 + 64 + tS) * HD + ddS;
      st0 = *(const s16x8*)(sb);
      st1 = *(const s16x8*)(sb + 8 * HD);
      st2 = *(const s16x8*)(sb + 16 * HD);
      st3 = *(const s16x8*)(sb + 24 * HD);
      st4 = *(const s16x8*)(sb + 32 * HD);
      st5 = *(const s16x8*)(sb + 40 * HD);
      st6 = *(const s16x8*)(sb + 48 * HD);
      st7 = *(const s16x8*)(sb + 56 * HD);
    }
    // tiled V^T: chunk base = t0*HD, d-row stride 64 elems (128B)
    const unsigned short* vb = kvT + (size_t)t0 * HD + (size_t)(wave * 64 + col) * 64 + grp * 8;
    s16x8 vf00 = *(const s16x8*)(vb);
    s16x8 vf01 = *(const s16x8*)(vb + 32);
    s16x8 vf10 = *(const s16x8*)(vb + 16 * 64);
    s16x8 vf11 = *(const s16x8*)(vb + 16 * 64 + 32);
    s16x8 vf20 = *(const s16x8*)(vb + 32 * 64);
    s16x8 vf21 = *(const s16x8*)(vb + 32 * 64 + 32);
    s16x8 vf30 = *(const s16x8*)(vb + 48 * 64);
    s16x8 vf31 = *(const s16x8*)(vb + 48 * 64 + 32);

    // ---- QK^T: four 16-key tiles ----
    f32x4 sA0 = z4, sA1 = z4, sA2 = z4, sA3 = z4;
    __builtin_amdgcn_s_setprio(1);
#define QKS(ko, qf) { \
      s16x8 b0 = *(const s16x8*)&kv_s[col * 264 + (ko) * 32 + grp * 8]; \
      s16x8 b1 = *(const s16x8*)&kv_s[(16 + col) * 264 + (ko) * 32 + grp * 8]; \
      s16x8 b2 = *(const s16x8*)&kv_s[(32 + col) * 264 + (ko) * 32 + grp * 8]; \
      s16x8 b3 = *(const s16x8*)&kv_s[(48 + col) * 264 + (ko) * 32 + grp * 8]; \
      sA0 = MFMA(qf, b0, sA0); sA1 = MFMA(qf, b1, sA1); \
      sA2 = MFMA(qf, b2, sA2); sA3 = MFMA(qf, b3, sA3); }
    QKS(0, qf0) QKS(1, qf1) QKS(2, qf2) QKS(3, qf3)
    QKS(4, qf4) QKS(5, qf5) QKS(6, qf6) QKS(7, qf7)
    __builtin_amdgcn_s_setprio(0);

    // ---- scale + causal mask ----
#define MASKR(r) { int sg = qrow + grp * 4 + (r); \
    sA0[r] = (t0 + col <= sg)      ? sA0[r] * SCALE : -1e30f; \
    sA1[r] = (t0 + 16 + col <= sg) ? sA1[r] * SCALE : -1e30f; \
    sA2[r] = (t0 + 32 + col <= sg) ? sA2[r] * SCALE : -1e30f; \
    sA3[r] = (t0 + 48 + col <= sg) ? sA3[r] * SCALE : -1e30f; }
    MASKR(0) MASKR(1) MASKR(2) MASKR(3)

    // ---- online softmax: row max -> alpha (l deferred) ----
    float a0, a1, a2, a3;
#define MAXR(r, mr, ar) { \
    float v = fmaxf(fmaxf(sA0[r], sA1[r]), fmaxf(sA2[r], sA3[r])); \
    v = fmaxf(v, __shfl_xor(v, 1)); v = fmaxf(v, __shfl_xor(v, 2)); \
    v = fmaxf(v, __shfl_xor(v, 4)); v = fmaxf(v, __shfl_xor(v, 8)); \
    float mn = fmaxf(mr, v); ar = __expf(mr - mn); mr = mn; }
    MAXR(0, m0r, a0) MAXR(1, m1r, a1) MAXR(2, m2r, a2) MAXR(3, m3r, a3)

    // ---- p, per-lane partial l, p_s writes ----
#define PROW(r, mr, lpr, ar) { \
    float p0 = __expf(sA0[r] - mr); float p1 = __expf(sA1[r] - mr); \
    float p2 = __expf(sA2[r] - mr); float p3 = __expf(sA3[r] - mr); \
    lpr = lpr * ar + (p0 + p1) + (p2 + p3); \
    int prow = (wave * 16 + grp * 4 + (r)) * 72; \
    p_s[prow + col] = f2bf(p0);      p_s[prow + 16 + col] = f2bf(p1); \
    p_s[prow + 32 + col] = f2bf(p2); p_s[prow + 48 + col] = f2bf(p3); }
    PROW(0, m0r, lp0, a0) PROW(1, m1r, lp1, a1) PROW(2, m2r, lp2, a2) PROW(3, m3r, lp3, a3)

    if (col == 0) {
      alpha_s[wave * 16 + grp * 4 + 0] = a0;
      alpha_s[wave * 16 + grp * 4 + 1] = a1;
      alpha_s[wave * 16 + grp * 4 + 2] = a2;
      alpha_s[wave * 16 + grp * 4 + 3] = a3;
    }
    __syncthreads();   // p_s/alpha_s ready; kv_s(ch) reads complete

    // ---- commit prefetched next chunk into kv_s ----
    if (havest) {
      *(s16x8*)&kv_s[tS * 264 + ddS]        = st0;
      *(s16x8*)&kv_s[(tS + 8) * 264 + ddS]  = st1;
      *(s16x8*)&kv_s[(tS + 16) * 264 + ddS] = st2;
      *(s16x8*)&kv_s[(tS + 24) * 264 + ddS] = st3;
      *(s16x8*)&kv_s[(tS + 32) * 264 + ddS] = st4;
      *(s16x8*)&kv_s[(tS + 40) * 264 + ddS] = st5;
      *(s16x8*)&kv_s[(tS + 48) * 264 + ddS] = st6;
      *(s16x8*)&kv_s[(tS + 56) * 264 + ddS] = st7;
    }

    // ---- rescale o-accs (alpha broadcast from LDS) ----
#define RESC(i) { f32x4 av = (f32x4){alpha_s[(i)*16 + grp*4 + 0], alpha_s[(i)*16 + grp*4 + 1], \
                                     alpha_s[(i)*16 + grp*4 + 2], alpha_s[(i)*16 + grp*4 + 3]}; \
    o##i##0 *= av; o##i##1 *= av; o##i##2 *= av; o##i##3 *= av; }
    RESC(0) RESC(1) RESC(2) RESC(3)

    // ---- PV: d-partition, K=64 in two halves, vf from prefetched regs ----
    s16x8 pf00 = *(const s16x8*)&p_s[(0 * 16 + col) * 72 + grp * 8];
    s16x8 pf01 = *(const s16x8*)&p_s[(0 * 16 + col) * 72 + 32 + grp * 8];
    s16x8 pf10 = *(const s16x8*)&p_s[(1 * 16 + col) * 72 + grp * 8];
    s16x8 pf11 = *(const s16x8*)&p_s[(1 * 16 + col) * 72 + 32 + grp * 8];
    s16x8 pf20 = *(const s16x8*)&p_s[(2 * 16 + col) * 72 + grp * 8];
    s16x8 pf21 = *(const s16x8*)&p_s[(2 * 16 + col) * 72 + 32 + grp * 8];
    s16x8 pf30 = *(const s16x8*)&p_s[(3 * 16 + col) * 72 + grp * 8];
    s16x8 pf31 = *(const s16x8*)&p_s[(3 * 16 + col) * 72 + 32 + grp * 8];
    __builtin_amdgcn_s_setprio(1);
#define PVJ(j) { \
      o0##j = MFMA(pf00, vf##j##0, o0##j); o0##j = MFMA(pf01, vf##j##1, o0##j); \
      o1##j = MFMA(pf10, vf##j##0, o1##j); o1##j = MFMA(pf11, vf##j##1, o1##j); \
      o2##j = MFMA(pf20, vf##j##0, o2##j); o2##j = MFMA(pf21, vf##j##1, o2##j); \
      o3##j = MFMA(pf30, vf##j##0, o3##j); o3##j = MFMA(pf31, vf##j##1, o3##j); }
    PVJ(0) PVJ(1) PVJ(2) PVJ(3)
    __builtin_amdgcn_s_setprio(0);
  }

  // ---- final l reduction + inv broadcast ----
  const float sk = sink[h];
  {
#define LRED(lpr) { lpr += __shfl_xor(lpr, 1); lpr += __shfl_xor(lpr, 2); \
                    lpr += __shfl_xor(lpr, 4); lpr += __shfl_xor(lpr, 8); }
    LRED(lp0) LRED(lp1) LRED(lp2) LRED(lp3)
    float i0 = 1.f / (lp0 + __expf(sk - m0r));
    float i1 = 1.f / (lp1 + __expf(sk - m1r));
    float i2 = 1.f / (lp2 + __expf(sk - m2r));
    float i3 = 1.f / (lp3 + __expf(sk - m3r));
    if (col == 0) {
      inv_s[wave * 16 + grp * 4 + 0] = i0;
      inv_s[wave * 16 + grp * 4 + 1] = i1;
      inv_s[wave * 16 + grp * 4 + 2] = i2;
      inv_s[wave * 16 + grp * 4 + 3] = i3;
    }
  }
  __syncthreads();

  // ---- epilogue: normalize, conj-RoPE (wave 3 owns dims 192..255), store ----
#define EPIJ(i, j, onam, ivv) { \
    float v0 = onam[0] * ivv[0]; float v1 = onam[1] * ivv[1]; \
    float v2 = onam[2] * ivv[2]; float v3 = onam[3] * ivv[3]; \
    if (wave == 3) { \
      int jr = ((j) * 16 + col) >> 1; \
      float f0 = freqs[(size_t)(q0 + (i) * 16 + grp * 4 + 0) * 32 + jr]; \
      float f1 = freqs[(size_t)(q0 + (i) * 16 + grp * 4 + 1) * 32 + jr]; \
      float f2 = freqs[(size_t)(q0 + (i) * 16 + grp * 4 + 2) * 32 + jr]; \
      float f3 = freqs[(size_t)(q0 + (i) * 16 + grp * 4 + 3) * 32 + jr]; \
      float p0 = __shfl_xor(v0, 1), p1 = __shfl_xor(v1, 1); \
      float p2 = __shfl_xor(v2, 1), p3 = __shfl_xor(v3, 1); \
      v0 = (col & 1) ? (v0 * cosf(f0) - p0 * sinf(f0)) : (v0 * cosf(f0) + p0 * sinf(f0)); \
      v1 = (col & 1) ? (v1 * cosf(f1) - p1 * sinf(f1)) : (v1 * cosf(f1) + p1 * sinf(f1)); \
      v2 = (col & 1) ? (v2 * cosf(f2) - p2 * sinf(f2)) : (v2 * cosf(f2) + p2 * sinf(f2)); \
      v3 = (col & 1) ? (v3 * cosf(f3) - p3 * sinf(f3)) : (v3 * cosf(f3) + p3 * sinf(f3)); \
    } \
    size_t obase = (size_t)(q0 + (i) * 16 + grp * 4) * (NH * HD) + (size_t)h * HD + \
                   wave * 64 + (j) * 16 + col; \
    ob[obase] = f2bf(v0); ob[obase + (NH * HD)] = f2bf(v1); \
    ob[obase + 2 * (NH * HD)] = f2bf(v2); ob[obase + 3 * (NH * HD)] = f2bf(v3); }
#define EPII(i) { \
    f32x4 ivv = (f32x4){inv_s[(i)*16 + grp*4 + 0], inv_s[(i)*16 + grp*4 + 1], \
                        inv_s[(i)*16 + grp*4 + 2], inv_s[(i)*16 + grp*4 + 3]}; \
    EPIJ(i, 0, o##i##0, ivv) EPIJ(i, 1, o##i##1, ivv) \
    EPIJ(i, 2, o##i##2, ivv) EPIJ(i, 3, o##i##3, ivv) }
  EPII(0) EPII(1) EPII(2) EPII(3)
}

extern "C" void kernel_launch(void* const* d_in, const int* in_sizes, int n_in,
                              void* d_out, int out_size, void* d_ws, size_t ws_size,
                              hipStream_t stream) {
  const float* x         = (const float*)d_in[0];
  const float* freqs     = (const float*)d_in[1];
  const float* wq_a      = (const float*)d_in[2];
  const float* q_norm_w  = (const float*)d_in[3];
  const float* wq_b      = (const float*)d_in[4];
  const float* wkv       = (const float*)d_in[5];
  const float* kv_norm_w = (const float*)d_in[6];
  const float* wo_a_w    = (const float*)d_in[7];
  const float* wo_b      = (const float*)d_in[8];
  const float* sink      = (const float*)d_in[9];
  float* out = (float*)d_out;

  // Workspace (byte offsets, 55 MB total):
  //  [0,4M)    qa_bf
  //  [4M,20M)  qa fp32 partials (g1 split-2, 2x8MB) -> then q_bf (g3 out).
  //            After attn: orb_bf [4M,12M), wob_bf [12M,20M)
  //  [20M,36M) o_bf (attn out); x_bf [20M,28M) dead before attn writes.
  //  [28M,44M) kv fp32 partials (g5 split-8, 8x2MB): written after g3 (wqa/wqb
  //            dead), consumed by kv_combine8 before attn writes o_bf.
  //  [36M,40M) wqa_bf  [40M,48M) wqb_bf  [48M,49M) wkv_bf
  //  [49M,53M) woa_bf  [53M,54M) kv_bf  [54M,55M) kvT_bf
  char* ws = (char*)d_ws;
  const size_t MB = 1024 * 1024;
  unsigned short* qa_bf   = (unsigned short*)(ws + 0 * MB);
  float*          qa_p    = (float*)(ws + 4 * MB);
  unsigned short* q_bf    = (unsigned short*)(ws + 4 * MB);
  unsigned short* orb_bf  = (unsigned short*)(ws + 4 * MB);
  unsigned short* wob_bf  = (unsigned short*)(ws + 12 * MB);
  unsigned short* o_bf    = (unsigned short*)(ws + 20 * MB);
  unsigned short* x_bf    = (unsigned short*)(ws + 20 * MB);
  float*          kv_p    = (float*)(ws + 28 * MB);
  unsigned short* wqa_bf  = (unsigned short*)(ws + 36 * MB);
  unsigned short* wqb_bf  = (unsigned short*)(ws + 40 * MB);
  unsigned short* wkv_bf  = (unsigned short*)(ws + 48 * MB);
  unsigned short* woa_bf  = (unsigned short*)(ws + 49 * MB);
  unsigned short* kv_bf   = (unsigned short*)(ws + 53 * MB);
  unsigned short* kvT_bf  = (unsigned short*)(ws + 54 * MB);

  dim3 blk(256);

  // 0) fused fp32 -> bf16 conversion of the 5 pre-attention tensors
  conv5<<<dim3(12800), blk, 0, stream>>>(x, wq_a, wq_b, wkv, wo_a_w,
                                         x_bf, wqa_bf, wqb_bf, wkv_bf, woa_bf);

  // 1) qa partials = x @ wq_a^T, split-K x2, BN=64 (grid 512 blocks) -> fp32
  gemm_bf16<64><<<dim3(QL / 64, S_LEN / 128, 2), blk, 0, stream>>>(
      x_bf, wqa_bf, qa_p, HID / 2, HID, HID, QL,
      (long)(HID / 2), (long)(HID / 2), (long)S_LEN * QL, 0);
  // 2) combine + RMS -> qa_bf
  rms_combine2<<<dim3(S_LEN), blk, 0, stream>>>(qa_p, qa_bf, q_norm_w);
  // 3) q = qa @ wq_b^T  (2048x4096, K=1024) -> bf16 RAW (norm fused into attn)
  gemm_bf16<128><<<dim3(NH * HD / 128, S_LEN / 128, 1), blk, 0, stream>>>(
      qa_bf, wqb_bf, q_bf, QL, QL, QL, NH * HD, 0, 0, 0, 1);
  // 4) kv partials = x @ wkv^T, split-K x8, BN=64 (grid 512 blocks) -> fp32
  gemm_bf16<64><<<dim3(HD / 64, S_LEN / 128, 8), blk, 0, stream>>>(
      x_bf, wkv_bf, kv_p, HID / 8, HID, HID, HD,
      (long)(HID / 8), (long)(HID / 8), (long)S_LEN * HD, 0);
  // 5) combine + RMS + RoPE -> kv_bf + kvT (tiled)
  kv_combine8<<<dim3(S_LEN), blk, 0, stream>>>(kv_p, kv_norm_w, freqs, kv_bf, kvT_bf);
  // 6) flash attention (Q-norm/RoPE fused) -> o_bf
  attn_mfma<<<dim3(S_LEN / 64, NH), blk, 0, stream>>>(q_bf, kv_bf, kvT_bf, sink, freqs, o_bf);
  // 6b) convert wo_b into [12M,20M) — q_bf dead after attention
  f32_to_bf16<<<dim3(4096), blk, 0, stream>>>(wo_b, wob_bf, 4 * 1024 * 1024 / 4);
  // 7) grouped projection via z-grid, BN=64 (grid 512 blocks)
  gemm_bf16<64><<<dim3(OR_ / 64, S_LEN / 128, NG), blk, 0, stream>>>(
      o_bf, woa_bf, orb_bf, HPG * HD, NH * HD, HPG * HD, NG * OR_,
      (long)(HPG * HD), (long)OR_ * (HPG * HD), (long)OR_, 1);
  // 8) out = orb @ wo_b^T (2048x2048, K=2048) -> fp32, BN=64 (512 blocks)
  gemm_bf16<64><<<dim3(HID / 64, S_LEN / 128, 1), blk, 0, stream>>>(
      orb_bf, wob_bf, out, NG * OR_, NG * OR_, NG * OR_, HID, 0, 0, 0, 0);
}

// Round 15
// 359.482 us; speedup vs baseline: 1.0636x; 1.0636x over previous
//
#include <hip/hip_runtime.h>
#include <hip/hip_bf16.h>

// Problem constants (B=1)
#define S_LEN 2048
#define HID 2048
#define NH 16
#define HD 256
#define NROT 64
#define NOPE 192
#define QL 1024
#define OR_ 512
#define NG 4
#define HPG 4
#define EPS 1e-6f
#define SCALE 0.0625f   // 256^-0.5

typedef __bf16 bf16x8 __attribute__((ext_vector_type(8)));
typedef short s16x8 __attribute__((ext_vector_type(8)));
typedef float f32x4 __attribute__((ext_vector_type(4)));

#define MFMA(a, b, c) __builtin_amdgcn_mfma_f32_16x16x32_bf16( \
    __builtin_bit_cast(bf16x8, a), __builtin_bit_cast(bf16x8, b), c, 0, 0, 0)

__device__ __forceinline__ unsigned short f2bf(float x) {
  unsigned int u = __builtin_bit_cast(unsigned int, x);
  u += 0x7FFFu + ((u >> 16) & 1u);   // RNE
  return (unsigned short)(u >> 16);
}
__device__ __forceinline__ float bf2f(unsigned short b) {
  unsigned int u = ((unsigned int)b) << 16;
  return __builtin_bit_cast(float, u);
}

// async global->LDS 16B: dest must be wave-uniform base + lane*16 (linear LDS)
#define GLD_LDS16(gp, lp) __builtin_amdgcn_global_load_lds( \
    (__attribute__((address_space(1))) void*)(gp), \
    (__attribute__((address_space(3))) void*)(lp), 16, 0, 0)

// ---------------- fp32 -> bf16 convert (single tensor) ----------------
__global__ __launch_bounds__(256) void f32_to_bf16(const float* __restrict__ in,
                                                   unsigned short* __restrict__ out, int n4) {
  int i = blockIdx.x * 256 + threadIdx.x;
  if (i < n4) {
    float4 v = ((const float4*)in)[i];
    ushort4 o;
    o.x = f2bf(v.x); o.y = f2bf(v.y); o.z = f2bf(v.z); o.w = f2bf(v.w);
    ((ushort4*)out)[i] = o;
  }
}

// ---------------- fused convert of the 5 pre-attention tensors ----------------
__global__ __launch_bounds__(256) void conv5(
    const float* __restrict__ x, const float* __restrict__ wqa,
    const float* __restrict__ wqb, const float* __restrict__ wkv,
    const float* __restrict__ woa,
    unsigned short* __restrict__ xo, unsigned short* __restrict__ wqao,
    unsigned short* __restrict__ wqbo, unsigned short* __restrict__ wkvo,
    unsigned short* __restrict__ woao) {
  int i = blockIdx.x * 256 + threadIdx.x;
  const float* src; unsigned short* dst; int off;
  if (i < 1048576)      { src = x;   dst = xo;   off = i; }
  else if (i < 1572864) { src = wqa; dst = wqao; off = i - 1048576; }
  else if (i < 2621440) { src = wqb; dst = wqbo; off = i - 1572864; }
  else if (i < 2752512) { src = wkv; dst = wkvo; off = i - 2621440; }
  else                  { src = woa; dst = woao; off = i - 2752512; }
  float4 v = ((const float4*)src)[off];
  ushort4 o;
  o.x = f2bf(v.x); o.y = f2bf(v.y); o.z = f2bf(v.z); o.w = f2bf(v.w);
  ((ushort4*)dst)[off] = o;
}

// ------------- bf16 MFMA GEMM: C[M,N] = A[M,K] @ B[N,K]^T, tile 128xBN -------
// R10: global_load_lds width-16 staging (m97 pattern).
// R14: split-K via z-grid (aoffz/boffz = K-advance, coffz = partial stride).
// R15: BN=64 variant for N-narrow GEMMs (2 blocks/CU).
// R21: BK 32->64 — halves the vmcnt(0)-drain + s_barrier count per K (the
// measured ~20%/2-phase critical-path cost). LDS 32KB(BN=128)/24KB(BN=64),
// occupancy unchanged. Source-pre-swizzle chunk c <- c^(row&7) with matching
// read XOR (session-verified idiom from attn v7) pins frag-read bank
// conflicts at 8-way (naive BK=64 would be 16-way). All K used divide 64.
template <int BN>
__global__ __launch_bounds__(256, 2) void gemm_bf16(
    const unsigned short* __restrict__ A, const unsigned short* __restrict__ B,
    void* __restrict__ Cv, int K, int lda, int ldb, int ldc,
    long aoffz, long boffz, long coffz, int store_bf) {
  constexpr int NF = BN / 32;   // n-frags per wave
  __shared__ __align__(16) unsigned short As[128 * 64];
  __shared__ __align__(16) unsigned short Bs[BN * 64];
  A += (size_t)blockIdx.z * aoffz;
  B += (size_t)blockIdx.z * boffz;
  const int tid = threadIdx.x;
  const int wave = tid >> 6, lane = tid & 63;
  const int col = lane & 15, grp = lane >> 4;
  const int wm = wave >> 1, wn = wave & 1;
  const int m0 = blockIdx.y * 128, n0 = blockIdx.x * BN;

  f32x4 acc[4][NF];
#pragma unroll
  for (int i = 0; i < 4; ++i)
#pragma unroll
    for (int j = 0; j < NF; ++j) acc[i][j] = (f32x4){0.f, 0.f, 0.f, 0.f};

  for (int k0 = 0; k0 < K; k0 += 64) {
    // stage A (128x64) : 1024 16B-chunks, 4/thread; row = lin>>3, chunk = lin&7
    // linear LDS dest; global source chunk pre-swizzled by ^(row&7)
#pragma unroll
    for (int u = 0; u < 4; ++u) {
      int lin = u * 256 + tid;
      int r = lin >> 3, c = lin & 7;
      GLD_LDS16(A + (size_t)(m0 + r) * lda + k0 + (c ^ (r & 7)) * 8, &As[lin * 8]);
    }
    // stage B (BNx64): BN*8 chunks, BN/32 per thread
#pragma unroll
    for (int u = 0; u < BN / 32; ++u) {
      int lin = u * 256 + tid;
      int r = lin >> 3, c = lin & 7;
      GLD_LDS16(B + (size_t)(n0 + r) * ldb + k0 + (c ^ (r & 7)) * 8, &Bs[lin * 8]);
    }
    __syncthreads();
#pragma unroll
    for (int kk = 0; kk < 64; kk += 32) {
      s16x8 a[4], b[NF];
#pragma unroll
      for (int i = 0; i < 4; ++i) {
        int row = wm * 64 + i * 16 + col;
        int g = (kk >> 3) + grp;                 // global chunk of this frag
        a[i] = *(const s16x8*)&As[row * 64 + ((g ^ (row & 7)) * 8)];
      }
#pragma unroll
      for (int j = 0; j < NF; ++j) {
        int row = wn * (BN / 2) + j * 16 + col;
        int g = (kk >> 3) + grp;
        b[j] = *(const s16x8*)&Bs[row * 64 + ((g ^ (row & 7)) * 8)];
      }
#pragma unroll
      for (int i = 0; i < 4; ++i)
#pragma unroll
        for (int j = 0; j < NF; ++j)
          acc[i][j] = MFMA(a[i], b[j], acc[i][j]);
    }
    __syncthreads();
  }

  if (store_bf) {
    unsigned short* C = (unsigned short*)Cv + (size_t)blockIdx.z * coffz;
#pragma unroll
    for (int i = 0; i < 4; ++i)
#pragma unroll
      for (int j = 0; j < NF; ++j)
#pragma unroll
        for (int r = 0; r < 4; ++r)
          C[(size_t)(m0 + wm * 64 + i * 16 + grp * 4 + r) * ldc +
            n0 + wn * (BN / 2) + j * 16 + col] = f2bf(acc[i][j][r]);
  } else {
    float* C = (float*)Cv + (size_t)blockIdx.z * coffz;
#pragma unroll
    for (int i = 0; i < 4; ++i)
#pragma unroll
      for (int j = 0; j < NF; ++j)
#pragma unroll
        for (int r = 0; r < 4; ++r)
          C[(size_t)(m0 + wm * 64 + i * 16 + grp * 4 + r) * ldc +
            n0 + wn * (BN / 2) + j * 16 + col] = acc[i][j][r];
  }
}

// ---------------- split-K combine (2 partials) + RMSNorm -> bf16 ----------------
__global__ __launch_bounds__(256) void rms_combine2(const float* __restrict__ p,
                                                    unsigned short* __restrict__ out,
                                                    const float* __restrict__ w) {
  int row = blockIdx.x;
  const float* r0 = p + (size_t)row * QL;
  const float* r1 = r0 + 2097152;   // second partial (2048*1024 floats)
  __shared__ float buf[QL];
  __shared__ float red[256];
  float s = 0.f;
  for (int i = threadIdx.x; i < QL; i += 256) {
    float v = r0[i] + r1[i];
    buf[i] = v;
    s += v * v;
  }
  red[threadIdx.x] = s;
  __syncthreads();
  for (int off = 128; off > 0; off >>= 1) {
    if (threadIdx.x < off) red[threadIdx.x] += red[threadIdx.x + off];
    __syncthreads();
  }
  float r = rsqrtf(red[0] / (float)QL + EPS);
  for (int i = threadIdx.x; i < QL; i += 256)
    out[(size_t)row * QL + i] = f2bf(buf[i] * r * w[i]);
}

// ------- split-K combine (8 partials) + KV RMS + RoPE -> kv_bf + kvT -------
// R16: kvT is TILED [S/64][HD][64] (chunk-contiguous V^T).
__global__ __launch_bounds__(256) void kv_combine8(const float* __restrict__ p,
                                                   const float* __restrict__ w,
                                                   const float* __restrict__ freqs,
                                                   unsigned short* __restrict__ kv,
                                                   unsigned short* __restrict__ kvT) {
  int s = blockIdx.x;
  int d = threadIdx.x;
  const float* b = p + (size_t)s * HD + d;
  float v = 0.f;
#pragma unroll
  for (int z = 0; z < 8; ++z) v += b[(size_t)z * 524288];   // 2048*256 stride
  __shared__ float red[256];
  __shared__ float sm[256];
  red[d] = v * v;
  __syncthreads();
  for (int off = 128; off > 0; off >>= 1) {
    if (d < off) red[d] += red[d + off];
    __syncthreads();
  }
  float r = rsqrtf(red[0] / 256.0f + EPS);
  float nv = v * r * w[d];
  sm[d] = nv;
  __syncthreads();
  float outv = nv;
  if (d >= NOPE) {
    int j = (d - NOPE) >> 1;
    float f = freqs[(size_t)s * (NROT / 2) + j];
    float c = cosf(f), si = sinf(f);
    float x1 = sm[NOPE + 2 * j], x2 = sm[NOPE + 2 * j + 1];
    outv = ((d & 1) == 0) ? (x1 * c - x2 * si) : (x1 * si + x2 * c);
  }
  unsigned short ov = f2bf(outv);
  kv[(size_t)s * HD + d] = ov;
  kvT[(size_t)(s & ~63) * HD + d * 64 + (s & 63)] = ov;   // tiled V^T
}

// ---------------- MFMA flash attention v6 + fused Q-norm/RoPE (R17; FINAL) ----
// 64-key chunks, register prefetch of all global traffic, balanced CU pairing
// (R11), setprio on MFMA clusters (T5), tiled kvT (R16), fused Q RMS+RoPE (R17).
// R19: PV-pipeline (R18) spilled; R20 KV-split failed correctness. This v6
// structure is the verified local optimum: 4 restructure attempts all lost.
__global__ __launch_bounds__(256, 2) void attn_mfma(
    const unsigned short* __restrict__ qbf,   // (S, NH*HD) bf16 RAW (pre-norm)
    const unsigned short* __restrict__ kvbf,  // (S, HD) bf16
    const unsigned short* __restrict__ kvT,   // tiled [S/64][HD][64] bf16
    const float* __restrict__ sink,
    const float* __restrict__ freqs,
    unsigned short* __restrict__ ob) {        // (S, NH*HD) bf16
  __shared__ __align__(16) unsigned short kv_s[64 * 264];  // [t][d]
  __shared__ __align__(16) unsigned short p_s[64 * 72];    // [row][t] (64 t + 8 pad)
  __shared__ float alpha_s[64];
  __shared__ float inv_s[64];

  const int tid = threadIdx.x;
  const int wave = tid >> 6, lane = tid & 63;
  const int col = lane & 15, grp = lane >> 4;
  // balanced pairing remap: lin in [0,512)
  const int lin = blockIdx.y * gridDim.x + blockIdx.x;
  const int half = lin >> 8, li = lin & 255;
  const int tr = li & 31;
  const int h = (half == 0) ? (li >> 5) : 8 + (li >> 5);
  const int q0 = ((half == 0) ? (31 - tr) : tr) * 64;
  const int qrow = q0 + wave * 16;

  // Q fragments: 8 named s16x8 regs (32 VGPRs)
  const unsigned short* qbase =
      qbf + (size_t)(qrow + col) * (NH * HD) + (size_t)h * HD + grp * 8;
#define QDECL(ko, nam) s16x8 nam = *(const s16x8*)(qbase + (ko) * 32);
  QDECL(0, qf0) QDECL(1, qf1) QDECL(2, qf2) QDECL(3, qf3)
  QDECL(4, qf4) QDECL(5, qf5) QDECL(6, qf6) QDECL(7, qf7)

  // ---- R17 fused Q RMS + RoPE ----
  {
    float sq = 0.f;
#define QSQ(qf) { _Pragma("unroll") \
    for (int j = 0; j < 8; ++j) { float v = bf2f((unsigned short)qf[j]); sq += v * v; } }
    QSQ(qf0) QSQ(qf1) QSQ(qf2) QSQ(qf3) QSQ(qf4) QSQ(qf5) QSQ(qf6) QSQ(qf7)
    sq += __shfl_xor(sq, 16);
    sq += __shfl_xor(sq, 32);
    const float qr_ = rsqrtf(sq * (1.0f / 256.0f) + EPS);
#define QSC(qf) { _Pragma("unroll") \
    for (int j = 0; j < 8; ++j) qf[j] = (short)f2bf(bf2f((unsigned short)qf[j]) * qr_); }
    QSC(qf0) QSC(qf1) QSC(qf2) QSC(qf3) QSC(qf4) QSC(qf5)
    const float* fb = freqs + (size_t)(qrow + col) * (NROT / 2);
#define QSR(qf, jb) { _Pragma("unroll") \
    for (int u = 0; u < 4; ++u) { \
      float f = fb[(jb) + grp * 4 + u]; \
      float c = cosf(f), s = sinf(f); \
      float x1 = bf2f((unsigned short)qf[2 * u]) * qr_; \
      float x2 = bf2f((unsigned short)qf[2 * u + 1]) * qr_; \
      qf[2 * u]     = (short)f2bf(x1 * c - x2 * s); \
      qf[2 * u + 1] = (short)f2bf(x1 * s + x2 * c); } }
    QSR(qf6, 0) QSR(qf7, 16)
  }

  const f32x4 z4 = (f32x4){0.f, 0.f, 0.f, 0.f};
  float m0r = -1e30f, m1r = -1e30f, m2r = -1e30f, m3r = -1e30f;
  float lp0 = 0.f, lp1 = 0.f, lp2 = 0.f, lp3 = 0.f;   // per-lane partial l

#define FOR16(M) M(0,0,o00) M(0,1,o01) M(0,2,o02) M(0,3,o03) \
                 M(1,0,o10) M(1,1,o11) M(1,2,o12) M(1,3,o13) \
                 M(2,0,o20) M(2,1,o21) M(2,2,o22) M(2,3,o23) \
                 M(3,0,o30) M(3,1,o31) M(3,2,o32) M(3,3,o33)
#define DECLO(i, j, onam) f32x4 onam = z4;
  FOR16(DECLO)

  // Staging lane geometry: thread owns rows {tS+8k, k=0..7}, cols [ddS, ddS+8)
  const int tS = tid >> 5, ddS = (tid & 31) * 8;

  // Initial stage of chunk 0
  {
    const unsigned short* sb = kvbf + (size_t)tS * HD + ddS;
#pragma unroll
    for (int k = 0; k < 8; ++k)
      *(s16x8*)&kv_s[(tS + 8 * k) * 264 + ddS] = *(const s16x8*)(sb + (size_t)(8 * k) * HD);
  }

  const int nch = q0 / 64 + 1;
  for (int ch = 0; ch < nch; ++ch) {
    const int t0 = ch * 64;
    __syncthreads();   // kv_s(ch) ready; p_s/alpha_s(ch-1) consumed

    // ---- PREFETCH: next chunk staging (8) + this chunk's vf B-frags (8) ----
    const bool havest = (ch + 1 < nch);
    s16x8 st0 = {}, st1 = {}, st2 = {}, st3 = {}, st4 = {}, st5 = {}, st6 = {}, st7 = {};
    if (havest) {
      const unsigned short* sb = kvbf + (size_t)(t0 + 64 + tS) * HD + ddS;
      st0 = *(const s16x8*)(sb);
      st1 = *(const s16x8*)(sb + 8 * HD);
      st2 = *(const s16x8*)(sb + 16 * HD);
      st3 = *(const s16x8*)(sb + 24 * HD);
      st4 = *(const s16x8*)(sb + 32 * HD);
      st5 = *(const s16x8*)(sb + 40 * HD);
      st6 = *(const s16x8*)(sb + 48 * HD);
      st7 = *(const s16x8*)(sb + 56 * HD);
    }
    // tiled V^T: chunk base = t0*HD, d-row stride 64 elems (128B)
    const unsigned short* vb = kvT + (size_t)t0 * HD + (size_t)(wave * 64 + col) * 64 + grp * 8;
    s16x8 vf00 = *(const s16x8*)(vb);
    s16x8 vf01 = *(const s16x8*)(vb + 32);
    s16x8 vf10 = *(const s16x8*)(vb + 16 * 64);
    s16x8 vf11 = *(const s16x8*)(vb + 16 * 64 + 32);
    s16x8 vf20 = *(const s16x8*)(vb + 32 * 64);
    s16x8 vf21 = *(const s16x8*)(vb + 32 * 64 + 32);
    s16x8 vf30 = *(const s16x8*)(vb + 48 * 64);
    s16x8 vf31 = *(const s16x8*)(vb + 48 * 64 + 32);

    // ---- QK^T: four 16-key tiles ----
    f32x4 sA0 = z4, sA1 = z4, sA2 = z4, sA3 = z4;
    __builtin_amdgcn_s_setprio(1);
#define QKS(ko, qf) { \
      s16x8 b0 = *(const s16x8*)&kv_s[col * 264 + (ko) * 32 + grp * 8]; \
      s16x8 b1 = *(const s16x8*)&kv_s[(16 + col) * 264 + (ko) * 32 + grp * 8]; \
      s16x8 b2 = *(const s16x8*)&kv_s[(32 + col) * 264 + (ko) * 32 + grp * 8]; \
      s16x8 b3 = *(const s16x8*)&kv_s[(48 + col) * 264 + (ko) * 32 + grp * 8]; \
      sA0 = MFMA(qf, b0, sA0); sA1 = MFMA(qf, b1, sA1); \
      sA2 = MFMA(qf, b2, sA2); sA3 = MFMA(qf, b3, sA3); }
    QKS(0, qf0) QKS(1, qf1) QKS(2, qf2) QKS(3, qf3)
    QKS(4, qf4) QKS(5, qf5) QKS(6, qf6) QKS(7, qf7)
    __builtin_amdgcn_s_setprio(0);

    // ---- scale + causal mask ----
#define MASKR(r) { int sg = qrow + grp * 4 + (r); \
    sA0[r] = (t0 + col <= sg)      ? sA0[r] * SCALE : -1e30f; \
    sA1[r] = (t0 + 16 + col <= sg) ? sA1[r] * SCALE : -1e30f; \
    sA2[r] = (t0 + 32 + col <= sg) ? sA2[r] * SCALE : -1e30f; \
    sA3[r] = (t0 + 48 + col <= sg) ? sA3[r] * SCALE : -1e30f; }
    MASKR(0) MASKR(1) MASKR(2) MASKR(3)

    // ---- online softmax: row max -> alpha (l deferred) ----
    float a0, a1, a2, a3;
#define MAXR(r, mr, ar) { \
    float v = fmaxf(fmaxf(sA0[r], sA1[r]), fmaxf(sA2[r], sA3[r])); \
    v = fmaxf(v, __shfl_xor(v, 1)); v = fmaxf(v, __shfl_xor(v, 2)); \
    v = fmaxf(v, __shfl_xor(v, 4)); v = fmaxf(v, __shfl_xor(v, 8)); \
    float mn = fmaxf(mr, v); ar = __expf(mr - mn); mr = mn; }
    MAXR(0, m0r, a0) MAXR(1, m1r, a1) MAXR(2, m2r, a2) MAXR(3, m3r, a3)

    // ---- p, per-lane partial l, p_s writes ----
#define PROW(r, mr, lpr, ar) { \
    float p0 = __expf(sA0[r] - mr); float p1 = __expf(sA1[r] - mr); \
    float p2 = __expf(sA2[r] - mr); float p3 = __expf(sA3[r] - mr); \
    lpr = lpr * ar + (p0 + p1) + (p2 + p3); \
    int prow = (wave * 16 + grp * 4 + (r)) * 72; \
    p_s[prow + col] = f2bf(p0);      p_s[prow + 16 + col] = f2bf(p1); \
    p_s[prow + 32 + col] = f2bf(p2); p_s[prow + 48 + col] = f2bf(p3); }
    PROW(0, m0r, lp0, a0) PROW(1, m1r, lp1, a1) PROW(2, m2r, lp2, a2) PROW(3, m3r, lp3, a3)

    if (col == 0) {
      alpha_s[wave * 16 + grp * 4 + 0] = a0;
      alpha_s[wave * 16 + grp * 4 + 1] = a1;
      alpha_s[wave * 16 + grp * 4 + 2] = a2;
      alpha_s[wave * 16 + grp * 4 + 3] = a3;
    }
    __syncthreads();   // p_s/alpha_s ready; kv_s(ch) reads complete

    // ---- commit prefetched next chunk into kv_s ----
    if (havest) {
      *(s16x8*)&kv_s[tS * 264 + ddS]        = st0;
      *(s16x8*)&kv_s[(tS + 8) * 264 + ddS]  = st1;
      *(s16x8*)&kv_s[(tS + 16) * 264 + ddS] = st2;
      *(s16x8*)&kv_s[(tS + 24) * 264 + ddS] = st3;
      *(s16x8*)&kv_s[(tS + 32) * 264 + ddS] = st4;
      *(s16x8*)&kv_s[(tS + 40) * 264 + ddS] = st5;
      *(s16x8*)&kv_s[(tS + 48) * 264 + ddS] = st6;
      *(s16x8*)&kv_s[(tS + 56) * 264 + ddS] = st7;
    }

    // ---- rescale o-accs (alpha broadcast from LDS) ----
#define RESC(i) { f32x4 av = (f32x4){alpha_s[(i)*16 + grp*4 + 0], alpha_s[(i)*16 + grp*4 + 1], \
                                     alpha_s[(i)*16 + grp*4 + 2], alpha_s[(i)*16 + grp*4 + 3]}; \
    o##i##0 *= av; o##i##1 *= av; o##i##2 *= av; o##i##3 *= av; }
    RESC(0) RESC(1) RESC(2) RESC(3)

    // ---- PV: d-partition, K=64 in two halves, vf from prefetched regs ----
    s16x8 pf00 = *(const s16x8*)&p_s[(0 * 16 + col) * 72 + grp * 8];
    s16x8 pf01 = *(const s16x8*)&p_s[(0 * 16 + col) * 72 + 32 + grp * 8];
    s16x8 pf10 = *(const s16x8*)&p_s[(1 * 16 + col) * 72 + grp * 8];
    s16x8 pf11 = *(const s16x8*)&p_s[(1 * 16 + col) * 72 + 32 + grp * 8];
    s16x8 pf20 = *(const s16x8*)&p_s[(2 * 16 + col) * 72 + grp * 8];
    s16x8 pf21 = *(const s16x8*)&p_s[(2 * 16 + col) * 72 + 32 + grp * 8];
    s16x8 pf30 = *(const s16x8*)&p_s[(3 * 16 + col) * 72 + grp * 8];
    s16x8 pf31 = *(const s16x8*)&p_s[(3 * 16 + col) * 72 + 32 + grp * 8];
    __builtin_amdgcn_s_setprio(1);
#define PVJ(j) { \
      o0##j = MFMA(pf00, vf##j##0, o0##j); o0##j = MFMA(pf01, vf##j##1, o0##j); \
      o1##j = MFMA(pf10, vf##j##0, o1##j); o1##j = MFMA(pf11, vf##j##1, o1##j); \
      o2##j = MFMA(pf20, vf##j##0, o2##j); o2##j = MFMA(pf21, vf##j##1, o2##j); \
      o3##j = MFMA(pf30, vf##j##0, o3##j); o3##j = MFMA(pf31, vf##j##1, o3##j); }
    PVJ(0) PVJ(1) PVJ(2) PVJ(3)
    __builtin_amdgcn_s_setprio(0);
  }

  // ---- final l reduction + inv broadcast ----
  const float sk = sink[h];
  {
#define LRED(lpr) { lpr += __shfl_xor(lpr, 1); lpr += __shfl_xor(lpr, 2); \
                    lpr += __shfl_xor(lpr, 4); lpr += __shfl_xor(lpr, 8); }
    LRED(lp0) LRED(lp1) LRED(lp2) LRED(lp3)
    float i0 = 1.f / (lp0 + __expf(sk - m0r));
    float i1 = 1.f / (lp1 + __expf(sk - m1r));
    float i2 = 1.f / (lp2 + __expf(sk - m2r));
    float i3 = 1.f / (lp3 + __expf(sk - m3r));
    if (col == 0) {
      inv_s[wave * 16 + grp * 4 + 0] = i0;
      inv_s[wave * 16 + grp * 4 + 1] = i1;
      inv_s[wave * 16 + grp * 4 + 2] = i2;
      inv_s[wave * 16 + grp * 4 + 3] = i3;
    }
  }
  __syncthreads();

  // ---- epilogue: normalize, conj-RoPE (wave 3 owns dims 192..255), store ----
#define EPIJ(i, j, onam, ivv) { \
    float v0 = onam[0] * ivv[0]; float v1 = onam[1] * ivv[1]; \
    float v2 = onam[2] * ivv[2]; float v3 = onam[3] * ivv[3]; \
    if (wave == 3) { \
      int jr = ((j) * 16 + col) >> 1; \
      float f0 = freqs[(size_t)(q0 + (i) * 16 + grp * 4 + 0) * 32 + jr]; \
      float f1 = freqs[(size_t)(q0 + (i) * 16 + grp * 4 + 1) * 32 + jr]; \
      float f2 = freqs[(size_t)(q0 + (i) * 16 + grp * 4 + 2) * 32 + jr]; \
      float f3 = freqs[(size_t)(q0 + (i) * 16 + grp * 4 + 3) * 32 + jr]; \
      float p0 = __shfl_xor(v0, 1), p1 = __shfl_xor(v1, 1); \
      float p2 = __shfl_xor(v2, 1), p3 = __shfl_xor(v3, 1); \
      v0 = (col & 1) ? (v0 * cosf(f0) - p0 * sinf(f0)) : (v0 * cosf(f0) + p0 * sinf(f0)); \
      v1 = (col & 1) ? (v1 * cosf(f1) - p1 * sinf(f1)) : (v1 * cosf(f1) + p1 * sinf(f1)); \
      v2 = (col & 1) ? (v2 * cosf(f2) - p2 * sinf(f2)) : (v2 * cosf(f2) + p2 * sinf(f2)); \
      v3 = (col & 1) ? (v3 * cosf(f3) - p3 * sinf(f3)) : (v3 * cosf(f3) + p3 * sinf(f3)); \
    } \
    size_t obase = (size_t)(q0 + (i) * 16 + grp * 4) * (NH * HD) + (size_t)h * HD + \
                   wave * 64 + (j) * 16 + col; \
    ob[obase] = f2bf(v0); ob[obase + (NH * HD)] = f2bf(v1); \
    ob[obase + 2 * (NH * HD)] = f2bf(v2); ob[obase + 3 * (NH * HD)] = f2bf(v3); }
#define EPII(i) { \
    f32x4 ivv = (f32x4){inv_s[(i)*16 + grp*4 + 0], inv_s[(i)*16 + grp*4 + 1], \
                        inv_s[(i)*16 + grp*4 + 2], inv_s[(i)*16 + grp*4 + 3]}; \
    EPIJ(i, 0, o##i##0, ivv) EPIJ(i, 1, o##i##1, ivv) \
    EPIJ(i, 2, o##i##2, ivv) EPIJ(i, 3, o##i##3, ivv) }
  EPII(0) EPII(1) EPII(2) EPII(3)
}

extern "C" void kernel_launch(void* const* d_in, const int* in_sizes, int n_in,
                              void* d_out, int out_size, void* d_ws, size_t ws_size,
                              hipStream_t stream) {
  const float* x         = (const float*)d_in[0];
  const float* freqs     = (const float*)d_in[1];
  const float* wq_a      = (const float*)d_in[2];
  const float* q_norm_w  = (const float*)d_in[3];
  const float* wq_b      = (const float*)d_in[4];
  const float* wkv       = (const float*)d_in[5];
  const float* kv_norm_w = (const float*)d_in[6];
  const float* wo_a_w    = (const float*)d_in[7];
  const float* wo_b      = (const float*)d_in[8];
  const float* sink      = (const float*)d_in[9];
  float* out = (float*)d_out;

  // Workspace (byte offsets, 55 MB total):
  //  [0,4M)    qa_bf
  //  [4M,20M)  qa fp32 partials (g1 split-2, 2x8MB) -> then q_bf (g3 out).
  //            After attn: orb_bf [4M,12M), wob_bf [12M,20M)
  //  [20M,36M) o_bf (attn out); x_bf [20M,28M) dead before attn writes.
  //  [28M,44M) kv fp32 partials (g5 split-8, 8x2MB): written after g3 (wqa/wqb
  //            dead), consumed by kv_combine8 before attn writes o_bf.
  //  [36M,40M) wqa_bf  [40M,48M) wqb_bf  [48M,49M) wkv_bf
  //  [49M,53M) woa_bf  [53M,54M) kv_bf  [54M,55M) kvT_bf
  char* ws = (char*)d_ws;
  const size_t MB = 1024 * 1024;
  unsigned short* qa_bf   = (unsigned short*)(ws + 0 * MB);
  float*          qa_p    = (float*)(ws + 4 * MB);
  unsigned short* q_bf    = (unsigned short*)(ws + 4 * MB);
  unsigned short* orb_bf  = (unsigned short*)(ws + 4 * MB);
  unsigned short* wob_bf  = (unsigned short*)(ws + 12 * MB);
  unsigned short* o_bf    = (unsigned short*)(ws + 20 * MB);
  unsigned short* x_bf    = (unsigned short*)(ws + 20 * MB);
  float*          kv_p    = (float*)(ws + 28 * MB);
  unsigned short* wqa_bf  = (unsigned short*)(ws + 36 * MB);
  unsigned short* wqb_bf  = (unsigned short*)(ws + 40 * MB);
  unsigned short* wkv_bf  = (unsigned short*)(ws + 48 * MB);
  unsigned short* woa_bf  = (unsigned short*)(ws + 49 * MB);
  unsigned short* kv_bf   = (unsigned short*)(ws + 53 * MB);
  unsigned short* kvT_bf  = (unsigned short*)(ws + 54 * MB);

  dim3 blk(256);

  // 0) fused fp32 -> bf16 conversion of the 5 pre-attention tensors
  conv5<<<dim3(12800), blk, 0, stream>>>(x, wq_a, wq_b, wkv, wo_a_w,
                                         x_bf, wqa_bf, wqb_bf, wkv_bf, woa_bf);

  // 1) qa partials = x @ wq_a^T, split-K x2, BN=64 (grid 512 blocks) -> fp32
  gemm_bf16<64><<<dim3(QL / 64, S_LEN / 128, 2), blk, 0, stream>>>(
      x_bf, wqa_bf, qa_p, HID / 2, HID, HID, QL,
      (long)(HID / 2), (long)(HID / 2), (long)S_LEN * QL, 0);
  // 2) combine + RMS -> qa_bf
  rms_combine2<<<dim3(S_LEN), blk, 0, stream>>>(qa_p, qa_bf, q_norm_w);
  // 3) q = qa @ wq_b^T  (2048x4096, K=1024) -> bf16 RAW (norm fused into attn)
  gemm_bf16<128><<<dim3(NH * HD / 128, S_LEN / 128, 1), blk, 0, stream>>>(
      qa_bf, wqb_bf, q_bf, QL, QL, QL, NH * HD, 0, 0, 0, 1);
  // 4) kv partials = x @ wkv^T, split-K x8, BN=64 (grid 512 blocks) -> fp32
  gemm_bf16<64><<<dim3(HD / 64, S_LEN / 128, 8), blk, 0, stream>>>(
      x_bf, wkv_bf, kv_p, HID / 8, HID, HID, HD,
      (long)(HID / 8), (long)(HID / 8), (long)S_LEN * HD, 0);
  // 5) combine + RMS + RoPE -> kv_bf + kvT (tiled)
  kv_combine8<<<dim3(S_LEN), blk, 0, stream>>>(kv_p, kv_norm_w, freqs, kv_bf, kvT_bf);
  // 6) flash attention (Q-norm/RoPE fused) -> o_bf
  attn_mfma<<<dim3(S_LEN / 64, NH), blk, 0, stream>>>(q_bf, kv_bf, kvT_bf, sink, freqs, o_bf);
  // 6b) convert wo_b into [12M,20M) — q_bf dead after attention
  f32_to_bf16<<<dim3(4096), blk, 0, stream>>>(wo_b, wob_bf, 4 * 1024 * 1024 / 4);
  // 7) grouped projection via z-grid, BN=64 (grid 512 blocks)
  gemm_bf16<64><<<dim3(OR_ / 64, S_LEN / 128, NG), blk, 0, stream>>>(
      o_bf, woa_bf, orb_bf, HPG * HD, NH * HD, HPG * HD, NG * OR_,
      (long)(HPG * HD), (long)OR_ * (HPG * HD), (long)OR_, 1);
  // 8) out = orb @ wo_b^T (2048x2048, K=2048) -> fp32, BN=64 (512 blocks)
  gemm_bf16<64><<<dim3(HID / 64, S_LEN / 128, 1), blk, 0, stream>>>(
      orb_bf, wob_bf, out, NG * OR_, NG * OR_, NG * OR_, HID, 0, 0, 0, 0);
}

// Round 16
// 357.566 us; speedup vs baseline: 1.0693x; 1.0054x over previous
//
#include <hip/hip_runtime.h>
#include <hip/hip_bf16.h>

// Problem constants (B=1)
#define S_LEN 2048
#define HID 2048
#define NH 16
#define HD 256
#define NROT 64
#define NOPE 192
#define QL 1024
#define OR_ 512
#define NG 4
#define HPG 4
#define EPS 1e-6f
#define SCALE 0.0625f   // 256^-0.5

typedef __bf16 bf16x8 __attribute__((ext_vector_type(8)));
typedef short s16x8 __attribute__((ext_vector_type(8)));
typedef float f32x4 __attribute__((ext_vector_type(4)));

#define MFMA(a, b, c) __builtin_amdgcn_mfma_f32_16x16x32_bf16( \
    __builtin_bit_cast(bf16x8, a), __builtin_bit_cast(bf16x8, b), c, 0, 0, 0)

__device__ __forceinline__ unsigned short f2bf(float x) {
  unsigned int u = __builtin_bit_cast(unsigned int, x);
  u += 0x7FFFu + ((u >> 16) & 1u);   // RNE
  return (unsigned short)(u >> 16);
}
__device__ __forceinline__ float bf2f(unsigned short b) {
  unsigned int u = ((unsigned int)b) << 16;
  return __builtin_bit_cast(float, u);
}

// async global->LDS 16B: dest must be wave-uniform base + lane*16 (linear LDS)
#define GLD_LDS16(gp, lp) __builtin_amdgcn_global_load_lds( \
    (__attribute__((address_space(1))) void*)(gp), \
    (__attribute__((address_space(3))) void*)(lp), 16, 0, 0)

// ---------------- fp32 -> bf16 convert (single tensor) ----------------
__global__ __launch_bounds__(256) void f32_to_bf16(const float* __restrict__ in,
                                                   unsigned short* __restrict__ out, int n4) {
  int i = blockIdx.x * 256 + threadIdx.x;
  if (i < n4) {
    float4 v = ((const float4*)in)[i];
    ushort4 o;
    o.x = f2bf(v.x); o.y = f2bf(v.y); o.z = f2bf(v.z); o.w = f2bf(v.w);
    ((ushort4*)out)[i] = o;
  }
}

// ---------------- fused convert of the 5 pre-attention tensors ----------------
__global__ __launch_bounds__(256) void conv5(
    const float* __restrict__ x, const float* __restrict__ wqa,
    const float* __restrict__ wqb, const float* __restrict__ wkv,
    const float* __restrict__ woa,
    unsigned short* __restrict__ xo, unsigned short* __restrict__ wqao,
    unsigned short* __restrict__ wqbo, unsigned short* __restrict__ wkvo,
    unsigned short* __restrict__ woao) {
  int i = blockIdx.x * 256 + threadIdx.x;
  const float* src; unsigned short* dst; int off;
  if (i < 1048576)      { src = x;   dst = xo;   off = i; }
  else if (i < 1572864) { src = wqa; dst = wqao; off = i - 1048576; }
  else if (i < 2621440) { src = wqb; dst = wqbo; off = i - 1572864; }
  else if (i < 2752512) { src = wkv; dst = wkvo; off = i - 2621440; }
  else                  { src = woa; dst = woao; off = i - 2752512; }
  float4 v = ((const float4*)src)[off];
  ushort4 o;
  o.x = f2bf(v.x); o.y = f2bf(v.y); o.z = f2bf(v.z); o.w = f2bf(v.w);
  ((ushort4*)dst)[off] = o;
}

// ------------- bf16 MFMA GEMM: C[M,N] = A[M,K] @ B[N,K]^T, tile 128xBN -------
// R10: global_load_lds width-16 staging (m97 pattern).
// R14: split-K via z-grid (aoffz/boffz = K-advance, coffz = partial stride).
// R15: BN=64 variant for N-narrow GEMMs (2 blocks/CU).
// R21: BK 32->64 (-9% GEMM chain, confirmed). R22: BK 64->128 — halves the
// drain+barrier count again. m132's BK=128 cliff (3->2 blocks/CU) doesn't
// apply: we're already pinned at 2 blocks/CU; LDS 48KB(BN=64)/64KB(BN=128),
// 2 blocks fit in 160KB. Swizzle c^(row&7) still bijective on 4-bit chunk
// index; bank math unchanged (row stride 256B === 0 mod 32 banks, 2-way free).
// All K used (256/1024/2048 incl. split-K segments) divide 128.
template <int BN>
__global__ __launch_bounds__(256, 2) void gemm_bf16(
    const unsigned short* __restrict__ A, const unsigned short* __restrict__ B,
    void* __restrict__ Cv, int K, int lda, int ldb, int ldc,
    long aoffz, long boffz, long coffz, int store_bf) {
  constexpr int NF = BN / 32;   // n-frags per wave
  __shared__ __align__(16) unsigned short As[128 * 128];
  __shared__ __align__(16) unsigned short Bs[BN * 128];
  A += (size_t)blockIdx.z * aoffz;
  B += (size_t)blockIdx.z * boffz;
  const int tid = threadIdx.x;
  const int wave = tid >> 6, lane = tid & 63;
  const int col = lane & 15, grp = lane >> 4;
  const int wm = wave >> 1, wn = wave & 1;
  const int m0 = blockIdx.y * 128, n0 = blockIdx.x * BN;

  f32x4 acc[4][NF];
#pragma unroll
  for (int i = 0; i < 4; ++i)
#pragma unroll
    for (int j = 0; j < NF; ++j) acc[i][j] = (f32x4){0.f, 0.f, 0.f, 0.f};

  for (int k0 = 0; k0 < K; k0 += 128) {
    // stage A (128x128): 2048 16B-chunks, 8/thread; row = lin>>4, chunk = lin&15
    // linear LDS dest; global source chunk pre-swizzled by ^(row&7)
#pragma unroll
    for (int u = 0; u < 8; ++u) {
      int lin = u * 256 + tid;
      int r = lin >> 4, c = lin & 15;
      GLD_LDS16(A + (size_t)(m0 + r) * lda + k0 + (c ^ (r & 7)) * 8, &As[lin * 8]);
    }
    // stage B (BNx128): BN*16 chunks, BN/16 per thread
#pragma unroll
    for (int u = 0; u < BN / 16; ++u) {
      int lin = u * 256 + tid;
      int r = lin >> 4, c = lin & 15;
      GLD_LDS16(B + (size_t)(n0 + r) * ldb + k0 + (c ^ (r & 7)) * 8, &Bs[lin * 8]);
    }
    __syncthreads();
#pragma unroll
    for (int kk = 0; kk < 128; kk += 32) {
      s16x8 a[4], b[NF];
#pragma unroll
      for (int i = 0; i < 4; ++i) {
        int row = wm * 64 + i * 16 + col;
        int g = (kk >> 3) + grp;                 // global chunk of this frag
        a[i] = *(const s16x8*)&As[row * 128 + ((g ^ (row & 7)) * 8)];
      }
#pragma unroll
      for (int j = 0; j < NF; ++j) {
        int row = wn * (BN / 2) + j * 16 + col;
        int g = (kk >> 3) + grp;
        b[j] = *(const s16x8*)&Bs[row * 128 + ((g ^ (row & 7)) * 8)];
      }
#pragma unroll
      for (int i = 0; i < 4; ++i)
#pragma unroll
        for (int j = 0; j < NF; ++j)
          acc[i][j] = MFMA(a[i], b[j], acc[i][j]);
    }
    __syncthreads();
  }

  if (store_bf) {
    unsigned short* C = (unsigned short*)Cv + (size_t)blockIdx.z * coffz;
#pragma unroll
    for (int i = 0; i < 4; ++i)
#pragma unroll
      for (int j = 0; j < NF; ++j)
#pragma unroll
        for (int r = 0; r < 4; ++r)
          C[(size_t)(m0 + wm * 64 + i * 16 + grp * 4 + r) * ldc +
            n0 + wn * (BN / 2) + j * 16 + col] = f2bf(acc[i][j][r]);
  } else {
    float* C = (float*)Cv + (size_t)blockIdx.z * coffz;
#pragma unroll
    for (int i = 0; i < 4; ++i)
#pragma unroll
      for (int j = 0; j < NF; ++j)
#pragma unroll
        for (int r = 0; r < 4; ++r)
          C[(size_t)(m0 + wm * 64 + i * 16 + grp * 4 + r) * ldc +
            n0 + wn * (BN / 2) + j * 16 + col] = acc[i][j][r];
  }
}

// ---------------- split-K combine (2 partials) + RMSNorm -> bf16 ----------------
__global__ __launch_bounds__(256) void rms_combine2(const float* __restrict__ p,
                                                    unsigned short* __restrict__ out,
                                                    const float* __restrict__ w) {
  int row = blockIdx.x;
  const float* r0 = p + (size_t)row * QL;
  const float* r1 = r0 + 2097152;   // second partial (2048*1024 floats)
  __shared__ float buf[QL];
  __shared__ float red[256];
  float s = 0.f;
  for (int i = threadIdx.x; i < QL; i += 256) {
    float v = r0[i] + r1[i];
    buf[i] = v;
    s += v * v;
  }
  red[threadIdx.x] = s;
  __syncthreads();
  for (int off = 128; off > 0; off >>= 1) {
    if (threadIdx.x < off) red[threadIdx.x] += red[threadIdx.x + off];
    __syncthreads();
  }
  float r = rsqrtf(red[0] / (float)QL + EPS);
  for (int i = threadIdx.x; i < QL; i += 256)
    out[(size_t)row * QL + i] = f2bf(buf[i] * r * w[i]);
}

// ------- split-K combine (8 partials) + KV RMS + RoPE -> kv_bf + kvT -------
// R16: kvT is TILED [S/64][HD][64] (chunk-contiguous V^T).
__global__ __launch_bounds__(256) void kv_combine8(const float* __restrict__ p,
                                                   const float* __restrict__ w,
                                                   const float* __restrict__ freqs,
                                                   unsigned short* __restrict__ kv,
                                                   unsigned short* __restrict__ kvT) {
  int s = blockIdx.x;
  int d = threadIdx.x;
  const float* b = p + (size_t)s * HD + d;
  float v = 0.f;
#pragma unroll
  for (int z = 0; z < 8; ++z) v += b[(size_t)z * 524288];   // 2048*256 stride
  __shared__ float red[256];
  __shared__ float sm[256];
  red[d] = v * v;
  __syncthreads();
  for (int off = 128; off > 0; off >>= 1) {
    if (d < off) red[d] += red[d + off];
    __syncthreads();
  }
  float r = rsqrtf(red[0] / 256.0f + EPS);
  float nv = v * r * w[d];
  sm[d] = nv;
  __syncthreads();
  float outv = nv;
  if (d >= NOPE) {
    int j = (d - NOPE) >> 1;
    float f = freqs[(size_t)s * (NROT / 2) + j];
    float c = cosf(f), si = sinf(f);
    float x1 = sm[NOPE + 2 * j], x2 = sm[NOPE + 2 * j + 1];
    outv = ((d & 1) == 0) ? (x1 * c - x2 * si) : (x1 * si + x2 * c);
  }
  unsigned short ov = f2bf(outv);
  kv[(size_t)s * HD + d] = ov;
  kvT[(size_t)(s & ~63) * HD + d * 64 + (s & 63)] = ov;   // tiled V^T
}

// ---------------- MFMA flash attention v6 + fused Q-norm/RoPE (R17; FINAL) ----
// 64-key chunks, register prefetch of all global traffic, balanced CU pairing
// (R11), setprio on MFMA clusters (T5), tiled kvT (R16), fused Q RMS+RoPE (R17).
// R19: PV-pipeline (R18) spilled; R20 KV-split failed correctness. This v6
// structure is the verified local optimum: 4 restructure attempts all lost.
__global__ __launch_bounds__(256, 2) void attn_mfma(
    const unsigned short* __restrict__ qbf,   // (S, NH*HD) bf16 RAW (pre-norm)
    const unsigned short* __restrict__ kvbf,  // (S, HD) bf16
    const unsigned short* __restrict__ kvT,   // tiled [S/64][HD][64] bf16
    const float* __restrict__ sink,
    const float* __restrict__ freqs,
    unsigned short* __restrict__ ob) {        // (S, NH*HD) bf16
  __shared__ __align__(16) unsigned short kv_s[64 * 264];  // [t][d]
  __shared__ __align__(16) unsigned short p_s[64 * 72];    // [row][t] (64 t + 8 pad)
  __shared__ float alpha_s[64];
  __shared__ float inv_s[64];

  const int tid = threadIdx.x;
  const int wave = tid >> 6, lane = tid & 63;
  const int col = lane & 15, grp = lane >> 4;
  // balanced pairing remap: lin in [0,512)
  const int lin = blockIdx.y * gridDim.x + blockIdx.x;
  const int half = lin >> 8, li = lin & 255;
  const int tr = li & 31;
  const int h = (half == 0) ? (li >> 5) : 8 + (li >> 5);
  const int q0 = ((half == 0) ? (31 - tr) : tr) * 64;
  const int qrow = q0 + wave * 16;

  // Q fragments: 8 named s16x8 regs (32 VGPRs)
  const unsigned short* qbase =
      qbf + (size_t)(qrow + col) * (NH * HD) + (size_t)h * HD + grp * 8;
#define QDECL(ko, nam) s16x8 nam = *(const s16x8*)(qbase + (ko) * 32);
  QDECL(0, qf0) QDECL(1, qf1) QDECL(2, qf2) QDECL(3, qf3)
  QDECL(4, qf4) QDECL(5, qf5) QDECL(6, qf6) QDECL(7, qf7)

  // ---- R17 fused Q RMS + RoPE ----
  {
    float sq = 0.f;
#define QSQ(qf) { _Pragma("unroll") \
    for (int j = 0; j < 8; ++j) { float v = bf2f((unsigned short)qf[j]); sq += v * v; } }
    QSQ(qf0) QSQ(qf1) QSQ(qf2) QSQ(qf3) QSQ(qf4) QSQ(qf5) QSQ(qf6) QSQ(qf7)
    sq += __shfl_xor(sq, 16);
    sq += __shfl_xor(sq, 32);
    const float qr_ = rsqrtf(sq * (1.0f / 256.0f) + EPS);
#define QSC(qf) { _Pragma("unroll") \
    for (int j = 0; j < 8; ++j) qf[j] = (short)f2bf(bf2f((unsigned short)qf[j]) * qr_); }
    QSC(qf0) QSC(qf1) QSC(qf2) QSC(qf3) QSC(qf4) QSC(qf5)
    const float* fb = freqs + (size_t)(qrow + col) * (NROT / 2);
#define QSR(qf, jb) { _Pragma("unroll") \
    for (int u = 0; u < 4; ++u) { \
      float f = fb[(jb) + grp * 4 + u]; \
      float c = cosf(f), s = sinf(f); \
      float x1 = bf2f((unsigned short)qf[2 * u]) * qr_; \
      float x2 = bf2f((unsigned short)qf[2 * u + 1]) * qr_; \
      qf[2 * u]     = (short)f2bf(x1 * c - x2 * s); \
      qf[2 * u + 1] = (short)f2bf(x1 * s + x2 * c); } }
    QSR(qf6, 0) QSR(qf7, 16)
  }

  const f32x4 z4 = (f32x4){0.f, 0.f, 0.f, 0.f};
  float m0r = -1e30f, m1r = -1e30f, m2r = -1e30f, m3r = -1e30f;
  float lp0 = 0.f, lp1 = 0.f, lp2 = 0.f, lp3 = 0.f;   // per-lane partial l

#define FOR16(M) M(0,0,o00) M(0,1,o01) M(0,2,o02) M(0,3,o03) \
                 M(1,0,o10) M(1,1,o11) M(1,2,o12) M(1,3,o13) \
                 M(2,0,o20) M(2,1,o21) M(2,2,o22) M(2,3,o23) \
                 M(3,0,o30) M(3,1,o31) M(3,2,o32) M(3,3,o33)
#define DECLO(i, j, onam) f32x4 onam = z4;
  FOR16(DECLO)

  // Staging lane geometry: thread owns rows {tS+8k, k=0..7}, cols [ddS, ddS+8)
  const int tS = tid >> 5, ddS = (tid & 31) * 8;

  // Initial stage of chunk 0
  {
    const unsigned short* sb = kvbf + (size_t)tS * HD + ddS;
#pragma unroll
    for (int k = 0; k < 8; ++k)
      *(s16x8*)&kv_s[(tS + 8 * k) * 264 + ddS] = *(const s16x8*)(sb + (size_t)(8 * k) * HD);
  }

  const int nch = q0 / 64 + 1;
  for (int ch = 0; ch < nch; ++ch) {
    const int t0 = ch * 64;
    __syncthreads();   // kv_s(ch) ready; p_s/alpha_s(ch-1) consumed

    // ---- PREFETCH: next chunk staging (8) + this chunk's vf B-frags (8) ----
    const bool havest = (ch + 1 < nch);
    s16x8 st0 = {}, st1 = {}, st2 = {}, st3 = {}, st4 = {}, st5 = {}, st6 = {}, st7 = {};
    if (havest) {
      const unsigned short* sb = kvbf + (size_t)(t0 + 64 + tS) * HD + ddS;
      st0 = *(const s16x8*)(sb);
      st1 = *(const s16x8*)(sb + 8 * HD);
      st2 = *(const s16x8*)(sb + 16 * HD);
      st3 = *(const s16x8*)(sb + 24 * HD);
      st4 = *(const s16x8*)(sb + 32 * HD);
      st5 = *(const s16x8*)(sb + 40 * HD);
      st6 = *(const s16x8*)(sb + 48 * HD);
      st7 = *(const s16x8*)(sb + 56 * HD);
    }
    // tiled V^T: chunk base = t0*HD, d-row stride 64 elems (128B)
    const unsigned short* vb = kvT + (size_t)t0 * HD + (size_t)(wave * 64 + col) * 64 + grp * 8;
    s16x8 vf00 = *(const s16x8*)(vb);
    s16x8 vf01 = *(const s16x8*)(vb + 32);
    s16x8 vf10 = *(const s16x8*)(vb + 16 * 64);
    s16x8 vf11 = *(const s16x8*)(vb + 16 * 64 + 32);
    s16x8 vf20 = *(const s16x8*)(vb + 32 * 64);
    s16x8 vf21 = *(const s16x8*)(vb + 32 * 64 + 32);
    s16x8 vf30 = *(const s16x8*)(vb + 48 * 64);
    s16x8 vf31 = *(const s16x8*)(vb + 48 * 64 + 32);

    // ---- QK^T: four 16-key tiles ----
    f32x4 sA0 = z4, sA1 = z4, sA2 = z4, sA3 = z4;
    __builtin_amdgcn_s_setprio(1);
#define QKS(ko, qf) { \
      s16x8 b0 = *(const s16x8*)&kv_s[col * 264 + (ko) * 32 + grp * 8]; \
      s16x8 b1 = *(const s16x8*)&kv_s[(16 + col) * 264 + (ko) * 32 + grp * 8]; \
      s16x8 b2 = *(const s16x8*)&kv_s[(32 + col) * 264 + (ko) * 32 + grp * 8]; \
      s16x8 b3 = *(const s16x8*)&kv_s[(48 + col) * 264 + (ko) * 32 + grp * 8]; \
      sA0 = MFMA(qf, b0, sA0); sA1 = MFMA(qf, b1, sA1); \
      sA2 = MFMA(qf, b2, sA2); sA3 = MFMA(qf, b3, sA3); }
    QKS(0, qf0) QKS(1, qf1) QKS(2, qf2) QKS(3, qf3)
    QKS(4, qf4) QKS(5, qf5) QKS(6, qf6) QKS(7, qf7)
    __builtin_amdgcn_s_setprio(0);

    // ---- scale + causal mask ----
#define MASKR(r) { int sg = qrow + grp * 4 + (r); \
    sA0[r] = (t0 + col <= sg)      ? sA0[r] * SCALE : -1e30f; \
    sA1[r] = (t0 + 16 + col <= sg) ? sA1[r] * SCALE : -1e30f; \
    sA2[r] = (t0 + 32 + col <= sg) ? sA2[r] * SCALE : -1e30f; \
    sA3[r] = (t0 + 48 + col <= sg) ? sA3[r] * SCALE : -1e30f; }
    MASKR(0) MASKR(1) MASKR(2) MASKR(3)

    // ---- online softmax: row max -> alpha (l deferred) ----
    float a0, a1, a2, a3;
#define MAXR(r, mr, ar) { \
    float v = fmaxf(fmaxf(sA0[r], sA1[r]), fmaxf(sA2[r], sA3[r])); \
    v = fmaxf(v, __shfl_xor(v, 1)); v = fmaxf(v, __shfl_xor(v, 2)); \
    v = fmaxf(v, __shfl_xor(v, 4)); v = fmaxf(v, __shfl_xor(v, 8)); \
    float mn = fmaxf(mr, v); ar = __expf(mr - mn); mr = mn; }
    MAXR(0, m0r, a0) MAXR(1, m1r, a1) MAXR(2, m2r, a2) MAXR(3, m3r, a3)

    // ---- p, per-lane partial l, p_s writes ----
#define PROW(r, mr, lpr, ar) { \
    float p0 = __expf(sA0[r] - mr); float p1 = __expf(sA1[r] - mr); \
    float p2 = __expf(sA2[r] - mr); float p3 = __expf(sA3[r] - mr); \
    lpr = lpr * ar + (p0 + p1) + (p2 + p3); \
    int prow = (wave * 16 + grp * 4 + (r)) * 72; \
    p_s[prow + col] = f2bf(p0);      p_s[prow + 16 + col] = f2bf(p1); \
    p_s[prow + 32 + col] = f2bf(p2); p_s[prow + 48 + col] = f2bf(p3); }
    PROW(0, m0r, lp0, a0) PROW(1, m1r, lp1, a1) PROW(2, m2r, lp2, a2) PROW(3, m3r, lp3, a3)

    if (col == 0) {
      alpha_s[wave * 16 + grp * 4 + 0] = a0;
      alpha_s[wave * 16 + grp * 4 + 1] = a1;
      alpha_s[wave * 16 + grp * 4 + 2] = a2;
      alpha_s[wave * 16 + grp * 4 + 3] = a3;
    }
    __syncthreads();   // p_s/alpha_s ready; kv_s(ch) reads complete

    // ---- commit prefetched next chunk into kv_s ----
    if (havest) {
      *(s16x8*)&kv_s[tS * 264 + ddS]        = st0;
      *(s16x8*)&kv_s[(tS + 8) * 264 + ddS]  = st1;
      *(s16x8*)&kv_s[(tS + 16) * 264 + ddS] = st2;
      *(s16x8*)&kv_s[(tS + 24) * 264 + ddS] = st3;
      *(s16x8*)&kv_s[(tS + 32) * 264 + ddS] = st4;
      *(s16x8*)&kv_s[(tS + 40) * 264 + ddS] = st5;
      *(s16x8*)&kv_s[(tS + 48) * 264 + ddS] = st6;
      *(s16x8*)&kv_s[(tS + 56) * 264 + ddS] = st7;
    }

    // ---- rescale o-accs (alpha broadcast from LDS) ----
#define RESC(i) { f32x4 av = (f32x4){alpha_s[(i)*16 + grp*4 + 0], alpha_s[(i)*16 + grp*4 + 1], \
                                     alpha_s[(i)*16 + grp*4 + 2], alpha_s[(i)*16 + grp*4 + 3]}; \
    o##i##0 *= av; o##i##1 *= av; o##i##2 *= av; o##i##3 *= av; }
    RESC(0) RESC(1) RESC(2) RESC(3)

    // ---- PV: d-partition, K=64 in two halves, vf from prefetched regs ----
    s16x8 pf00 = *(const s16x8*)&p_s[(0 * 16 + col) * 72 + grp * 8];
    s16x8 pf01 = *(const s16x8*)&p_s[(0 * 16 + col) * 72 + 32 + grp * 8];
    s16x8 pf10 = *(const s16x8*)&p_s[(1 * 16 + col) * 72 + grp * 8];
    s16x8 pf11 = *(const s16x8*)&p_s[(1 * 16 + col) * 72 + 32 + grp * 8];
    s16x8 pf20 = *(const s16x8*)&p_s[(2 * 16 + col) * 72 + grp * 8];
    s16x8 pf21 = *(const s16x8*)&p_s[(2 * 16 + col) * 72 + 32 + grp * 8];
    s16x8 pf30 = *(const s16x8*)&p_s[(3 * 16 + col) * 72 + grp * 8];
    s16x8 pf31 = *(const s16x8*)&p_s[(3 * 16 + col) * 72 + 32 + grp * 8];
    __builtin_amdgcn_s_setprio(1);
#define PVJ(j) { \
      o0##j = MFMA(pf00, vf##j##0, o0##j); o0##j = MFMA(pf01, vf##j##1, o0##j); \
      o1##j = MFMA(pf10, vf##j##0, o1##j); o1##j = MFMA(pf11, vf##j##1, o1##j); \
      o2##j = MFMA(pf20, vf##j##0, o2##j); o2##j = MFMA(pf21, vf##j##1, o2##j); \
      o3##j = MFMA(pf30, vf##j##0, o3##j); o3##j = MFMA(pf31, vf##j##1, o3##j); }
    PVJ(0) PVJ(1) PVJ(2) PVJ(3)
    __builtin_amdgcn_s_setprio(0);
  }

  // ---- final l reduction + inv broadcast ----
  const float sk = sink[h];
  {
#define LRED(lpr) { lpr += __shfl_xor(lpr, 1); lpr += __shfl_xor(lpr, 2); \
                    lpr += __shfl_xor(lpr, 4); lpr += __shfl_xor(lpr, 8); }
    LRED(lp0) LRED(lp1) LRED(lp2) LRED(lp3)
    float i0 = 1.f / (lp0 + __expf(sk - m0r));
    float i1 = 1.f / (lp1 + __expf(sk - m1r));
    float i2 = 1.f / (lp2 + __expf(sk - m2r));
    float i3 = 1.f / (lp3 + __expf(sk - m3r));
    if (col == 0) {
      inv_s[wave * 16 + grp * 4 + 0] = i0;
      inv_s[wave * 16 + grp * 4 + 1] = i1;
      inv_s[wave * 16 + grp * 4 + 2] = i2;
      inv_s[wave * 16 + grp * 4 + 3] = i3;
    }
  }
  __syncthreads();

  // ---- epilogue: normalize, conj-RoPE (wave 3 owns dims 192..255), store ----
#define EPIJ(i, j, onam, ivv) { \
    float v0 = onam[0] * ivv[0]; float v1 = onam[1] * ivv[1]; \
    float v2 = onam[2] * ivv[2]; float v3 = onam[3] * ivv[3]; \
    if (wave == 3) { \
      int jr = ((j) * 16 + col) >> 1; \
      float f0 = freqs[(size_t)(q0 + (i) * 16 + grp * 4 + 0) * 32 + jr]; \
      float f1 = freqs[(size_t)(q0 + (i) * 16 + grp * 4 + 1) * 32 + jr]; \
      float f2 = freqs[(size_t)(q0 + (i) * 16 + grp * 4 + 2) * 32 + jr]; \
      float f3 = freqs[(size_t)(q0 + (i) * 16 + grp * 4 + 3) * 32 + jr]; \
      float p0 = __shfl_xor(v0, 1), p1 = __shfl_xor(v1, 1); \
      float p2 = __shfl_xor(v2, 1), p3 = __shfl_xor(v3, 1); \
      v0 = (col & 1) ? (v0 * cosf(f0) - p0 * sinf(f0)) : (v0 * cosf(f0) + p0 * sinf(f0)); \
      v1 = (col & 1) ? (v1 * cosf(f1) - p1 * sinf(f1)) : (v1 * cosf(f1) + p1 * sinf(f1)); \
      v2 = (col & 1) ? (v2 * cosf(f2) - p2 * sinf(f2)) : (v2 * cosf(f2) + p2 * sinf(f2)); \
      v3 = (col & 1) ? (v3 * cosf(f3) - p3 * sinf(f3)) : (v3 * cosf(f3) + p3 * sinf(f3)); \
    } \
    size_t obase = (size_t)(q0 + (i) * 16 + grp * 4) * (NH * HD) + (size_t)h * HD + \
                   wave * 64 + (j) * 16 + col; \
    ob[obase] = f2bf(v0); ob[obase + (NH * HD)] = f2bf(v1); \
    ob[obase + 2 * (NH * HD)] = f2bf(v2); ob[obase + 3 * (NH * HD)] = f2bf(v3); }
#define EPII(i) { \
    f32x4 ivv = (f32x4){inv_s[(i)*16 + grp*4 + 0], inv_s[(i)*16 + grp*4 + 1], \
                        inv_s[(i)*16 + grp*4 + 2], inv_s[(i)*16 + grp*4 + 3]}; \
    EPIJ(i, 0, o##i##0, ivv) EPIJ(i, 1, o##i##1, ivv) \
    EPIJ(i, 2, o##i##2, ivv) EPIJ(i, 3, o##i##3, ivv) }
  EPII(0) EPII(1) EPII(2) EPII(3)
}

extern "C" void kernel_launch(void* const* d_in, const int* in_sizes, int n_in,
                              void* d_out, int out_size, void* d_ws, size_t ws_size,
                              hipStream_t stream) {
  const float* x         = (const float*)d_in[0];
  const float* freqs     = (const float*)d_in[1];
  const float* wq_a      = (const float*)d_in[2];
  const float* q_norm_w  = (const float*)d_in[3];
  const float* wq_b      = (const float*)d_in[4];
  const float* wkv       = (const float*)d_in[5];
  const float* kv_norm_w = (const float*)d_in[6];
  const float* wo_a_w    = (const float*)d_in[7];
  const float* wo_b      = (const float*)d_in[8];
  const float* sink      = (const float*)d_in[9];
  float* out = (float*)d_out;

  // Workspace (byte offsets, 55 MB total):
  //  [0,4M)    qa_bf
  //  [4M,20M)  qa fp32 partials (g1 split-2, 2x8MB) -> then q_bf (g3 out).
  //            After attn: orb_bf [4M,12M), wob_bf [12M,20M)
  //  [20M,36M) o_bf (attn out); x_bf [20M,28M) dead before attn writes.
  //  [28M,44M) kv fp32 partials (g5 split-8, 8x2MB): written after g3 (wqa/wqb
  //            dead), consumed by kv_combine8 before attn writes o_bf.
  //  [36M,40M) wqa_bf  [40M,48M) wqb_bf  [48M,49M) wkv_bf
  //  [49M,53M) woa_bf  [53M,54M) kv_bf  [54M,55M) kvT_bf
  char* ws = (char*)d_ws;
  const size_t MB = 1024 * 1024;
  unsigned short* qa_bf   = (unsigned short*)(ws + 0 * MB);
  float*          qa_p    = (float*)(ws + 4 * MB);
  unsigned short* q_bf    = (unsigned short*)(ws + 4 * MB);
  unsigned short* orb_bf  = (unsigned short*)(ws + 4 * MB);
  unsigned short* wob_bf  = (unsigned short*)(ws + 12 * MB);
  unsigned short* o_bf    = (unsigned short*)(ws + 20 * MB);
  unsigned short* x_bf    = (unsigned short*)(ws + 20 * MB);
  float*          kv_p    = (float*)(ws + 28 * MB);
  unsigned short* wqa_bf  = (unsigned short*)(ws + 36 * MB);
  unsigned short* wqb_bf  = (unsigned short*)(ws + 40 * MB);
  unsigned short* wkv_bf  = (unsigned short*)(ws + 48 * MB);
  unsigned short* woa_bf  = (unsigned short*)(ws + 49 * MB);
  unsigned short* kv_bf   = (unsigned short*)(ws + 53 * MB);
  unsigned short* kvT_bf  = (unsigned short*)(ws + 54 * MB);

  dim3 blk(256);

  // 0) fused fp32 -> bf16 conversion of the 5 pre-attention tensors
  conv5<<<dim3(12800), blk, 0, stream>>>(x, wq_a, wq_b, wkv, wo_a_w,
                                         x_bf, wqa_bf, wqb_bf, wkv_bf, woa_bf);

  // 1) qa partials = x @ wq_a^T, split-K x2, BN=64 (grid 512 blocks) -> fp32
  gemm_bf16<64><<<dim3(QL / 64, S_LEN / 128, 2), blk, 0, stream>>>(
      x_bf, wqa_bf, qa_p, HID / 2, HID, HID, QL,
      (long)(HID / 2), (long)(HID / 2), (long)S_LEN * QL, 0);
  // 2) combine + RMS -> qa_bf
  rms_combine2<<<dim3(S_LEN), blk, 0, stream>>>(qa_p, qa_bf, q_norm_w);
  // 3) q = qa @ wq_b^T  (2048x4096, K=1024) -> bf16 RAW (norm fused into attn)
  gemm_bf16<128><<<dim3(NH * HD / 128, S_LEN / 128, 1), blk, 0, stream>>>(
      qa_bf, wqb_bf, q_bf, QL, QL, QL, NH * HD, 0, 0, 0, 1);
  // 4) kv partials = x @ wkv^T, split-K x8, BN=64 (grid 512 blocks) -> fp32
  gemm_bf16<64><<<dim3(HD / 64, S_LEN / 128, 8), blk, 0, stream>>>(
      x_bf, wkv_bf, kv_p, HID / 8, HID, HID, HD,
      (long)(HID / 8), (long)(HID / 8), (long)S_LEN * HD, 0);
  // 5) combine + RMS + RoPE -> kv_bf + kvT (tiled)
  kv_combine8<<<dim3(S_LEN), blk, 0, stream>>>(kv_p, kv_norm_w, freqs, kv_bf, kvT_bf);
  // 6) flash attention (Q-norm/RoPE fused) -> o_bf
  attn_mfma<<<dim3(S_LEN / 64, NH), blk, 0, stream>>>(q_bf, kv_bf, kvT_bf, sink, freqs, o_bf);
  // 6b) convert wo_b into [12M,20M) — q_bf dead after attention
  f32_to_bf16<<<dim3(4096), blk, 0, stream>>>(wo_b, wob_bf, 4 * 1024 * 1024 / 4);
  // 7) grouped projection via z-grid, BN=64 (grid 512 blocks)
  gemm_bf16<64><<<dim3(OR_ / 64, S_LEN / 128, NG), blk, 0, stream>>>(
      o_bf, woa_bf, orb_bf, HPG * HD, NH * HD, HPG * HD, NG * OR_,
      (long)(HPG * HD), (long)OR_ * (HPG * HD), (long)OR_, 1);
  // 8) out = orb @ wo_b^T (2048x2048, K=2048) -> fp32, BN=64 (512 blocks)
  gemm_bf16<64><<<dim3(HID / 64, S_LEN / 128, 1), blk, 0, stream>>>(
      orb_bf, wob_bf, out, NG * OR_, NG * OR_, NG * OR_, HID, 0, 0, 0, 0);
}

// Round 17
// 355.380 us; speedup vs baseline: 1.0759x; 1.0062x over previous
//
#include <hip/hip_runtime.h>
#include <hip/hip_bf16.h>

// Problem constants (B=1)
#define S_LEN 2048
#define HID 2048
#define NH 16
#define HD 256
#define NROT 64
#define NOPE 192
#define QL 1024
#define OR_ 512
#define NG 4
#define HPG 4
#define EPS 1e-6f
#define SCALE 0.0625f   // 256^-0.5

typedef __bf16 bf16x8 __attribute__((ext_vector_type(8)));
typedef short s16x8 __attribute__((ext_vector_type(8)));
typedef float f32x4 __attribute__((ext_vector_type(4)));

#define MFMA(a, b, c) __builtin_amdgcn_mfma_f32_16x16x32_bf16( \
    __builtin_bit_cast(bf16x8, a), __builtin_bit_cast(bf16x8, b), c, 0, 0, 0)

__device__ __forceinline__ unsigned short f2bf(float x) {
  unsigned int u = __builtin_bit_cast(unsigned int, x);
  u += 0x7FFFu + ((u >> 16) & 1u);   // RNE
  return (unsigned short)(u >> 16);
}
__device__ __forceinline__ float bf2f(unsigned short b) {
  unsigned int u = ((unsigned int)b) << 16;
  return __builtin_bit_cast(float, u);
}

// async global->LDS 16B: dest must be wave-uniform base + lane*16 (linear LDS)
#define GLD_LDS16(gp, lp) __builtin_amdgcn_global_load_lds( \
    (__attribute__((address_space(1))) void*)(gp), \
    (__attribute__((address_space(3))) void*)(lp), 16, 0, 0)

// ---------------- fp32 -> bf16 convert (single tensor) ----------------
__global__ __launch_bounds__(256) void f32_to_bf16(const float* __restrict__ in,
                                                   unsigned short* __restrict__ out, int n4) {
  int i = blockIdx.x * 256 + threadIdx.x;
  if (i < n4) {
    float4 v = ((const float4*)in)[i];
    ushort4 o;
    o.x = f2bf(v.x); o.y = f2bf(v.y); o.z = f2bf(v.z); o.w = f2bf(v.w);
    ((ushort4*)out)[i] = o;
  }
}

// ---------------- fused convert of the 5 pre-attention tensors ----------------
__global__ __launch_bounds__(256) void conv5(
    const float* __restrict__ x, const float* __restrict__ wqa,
    const float* __restrict__ wqb, const float* __restrict__ wkv,
    const float* __restrict__ woa,
    unsigned short* __restrict__ xo, unsigned short* __restrict__ wqao,
    unsigned short* __restrict__ wqbo, unsigned short* __restrict__ wkvo,
    unsigned short* __restrict__ woao) {
  int i = blockIdx.x * 256 + threadIdx.x;
  const float* src; unsigned short* dst; int off;
  if (i < 1048576)      { src = x;   dst = xo;   off = i; }
  else if (i < 1572864) { src = wqa; dst = wqao; off = i - 1048576; }
  else if (i < 2621440) { src = wqb; dst = wqbo; off = i - 1572864; }
  else if (i < 2752512) { src = wkv; dst = wkvo; off = i - 2621440; }
  else                  { src = woa; dst = woao; off = i - 2752512; }
  float4 v = ((const float4*)src)[off];
  ushort4 o;
  o.x = f2bf(v.x); o.y = f2bf(v.y); o.z = f2bf(v.z); o.w = f2bf(v.w);
  ((ushort4*)dst)[off] = o;
}

// ------------- bf16 MFMA GEMM: C[M,N] = A[M,K] @ B[N,K]^T, tile 128xBN -------
// R10 gl_lds staging; R14 split-K z-grid; R15 BN=64; R21/R22 BK=128 with
// chunk pre-swizzle c^(row&7) (bijective, bank-neutral).
template <int BN>
__global__ __launch_bounds__(256, 2) void gemm_bf16(
    const unsigned short* __restrict__ A, const unsigned short* __restrict__ B,
    void* __restrict__ Cv, int K, int lda, int ldb, int ldc,
    long aoffz, long boffz, long coffz, int store_bf) {
  constexpr int NF = BN / 32;   // n-frags per wave
  __shared__ __align__(16) unsigned short As[128 * 128];
  __shared__ __align__(16) unsigned short Bs[BN * 128];
  A += (size_t)blockIdx.z * aoffz;
  B += (size_t)blockIdx.z * boffz;
  const int tid = threadIdx.x;
  const int wave = tid >> 6, lane = tid & 63;
  const int col = lane & 15, grp = lane >> 4;
  const int wm = wave >> 1, wn = wave & 1;
  const int m0 = blockIdx.y * 128, n0 = blockIdx.x * BN;

  f32x4 acc[4][NF];
#pragma unroll
  for (int i = 0; i < 4; ++i)
#pragma unroll
    for (int j = 0; j < NF; ++j) acc[i][j] = (f32x4){0.f, 0.f, 0.f, 0.f};

  for (int k0 = 0; k0 < K; k0 += 128) {
#pragma unroll
    for (int u = 0; u < 8; ++u) {
      int lin = u * 256 + tid;
      int r = lin >> 4, c = lin & 15;
      GLD_LDS16(A + (size_t)(m0 + r) * lda + k0 + (c ^ (r & 7)) * 8, &As[lin * 8]);
    }
#pragma unroll
    for (int u = 0; u < BN / 16; ++u) {
      int lin = u * 256 + tid;
      int r = lin >> 4, c = lin & 15;
      GLD_LDS16(B + (size_t)(n0 + r) * ldb + k0 + (c ^ (r & 7)) * 8, &Bs[lin * 8]);
    }
    __syncthreads();
#pragma unroll
    for (int kk = 0; kk < 128; kk += 32) {
      s16x8 a[4], b[NF];
#pragma unroll
      for (int i = 0; i < 4; ++i) {
        int row = wm * 64 + i * 16 + col;
        int g = (kk >> 3) + grp;
        a[i] = *(const s16x8*)&As[row * 128 + ((g ^ (row & 7)) * 8)];
      }
#pragma unroll
      for (int j = 0; j < NF; ++j) {
        int row = wn * (BN / 2) + j * 16 + col;
        int g = (kk >> 3) + grp;
        b[j] = *(const s16x8*)&Bs[row * 128 + ((g ^ (row & 7)) * 8)];
      }
#pragma unroll
      for (int i = 0; i < 4; ++i)
#pragma unroll
        for (int j = 0; j < NF; ++j)
          acc[i][j] = MFMA(a[i], b[j], acc[i][j]);
    }
    __syncthreads();
  }

  if (store_bf) {
    unsigned short* C = (unsigned short*)Cv + (size_t)blockIdx.z * coffz;
#pragma unroll
    for (int i = 0; i < 4; ++i)
#pragma unroll
      for (int j = 0; j < NF; ++j)
#pragma unroll
        for (int r = 0; r < 4; ++r)
          C[(size_t)(m0 + wm * 64 + i * 16 + grp * 4 + r) * ldc +
            n0 + wn * (BN / 2) + j * 16 + col] = f2bf(acc[i][j][r]);
  } else {
    float* C = (float*)Cv + (size_t)blockIdx.z * coffz;
#pragma unroll
    for (int i = 0; i < 4; ++i)
#pragma unroll
      for (int j = 0; j < NF; ++j)
#pragma unroll
        for (int r = 0; r < 4; ++r)
          C[(size_t)(m0 + wm * 64 + i * 16 + grp * 4 + r) * ldc +
            n0 + wn * (BN / 2) + j * 16 + col] = acc[i][j][r];
  }
}

// ------- R23: merged qa + kv partial GEMM (both depend only on conv5) -------
// z in [0,2): qa split-K x2 (K=1024, C=qa_p, ldc=QL, grid x<16)
// z in [2,6): kv split-K x4 (K=512,  C=kv_p, ldc=HD, grid x<4; others exit)
// Same A (x_bf), lda=ldb=HID, BN=64, BK=128, fp32 store. 768 real blocks
// = 3 blocks/CU during this phase (was 2 sequential launches at 2/CU).
__global__ __launch_bounds__(256, 2) void gemm_qakv(
    const unsigned short* __restrict__ xb, const unsigned short* __restrict__ wqa,
    const unsigned short* __restrict__ wkv, float* __restrict__ qa_p,
    float* __restrict__ kv_p) {
  constexpr int BN = 64, NF = 2;
  const unsigned short* A;
  const unsigned short* B;
  float* C;
  int K, ldc;
  const int z = blockIdx.z;
  if (z < 2) {
    A = xb + z * 1024; B = wqa + z * 1024;
    C = qa_p + (size_t)z * S_LEN * QL; K = 1024; ldc = QL;
  } else {
    if (blockIdx.x >= HD / 64) return;   // uniform whole-block exit
    int zz = z - 2;
    A = xb + zz * 512; B = wkv + zz * 512;
    C = kv_p + (size_t)zz * S_LEN * HD; K = 512; ldc = HD;
  }
  __shared__ __align__(16) unsigned short As[128 * 128];
  __shared__ __align__(16) unsigned short Bs[BN * 128];
  const int tid = threadIdx.x;
  const int wave = tid >> 6, lane = tid & 63;
  const int col = lane & 15, grp = lane >> 4;
  const int wm = wave >> 1, wn = wave & 1;
  const int m0 = blockIdx.y * 128, n0 = blockIdx.x * BN;

  f32x4 acc[4][NF];
#pragma unroll
  for (int i = 0; i < 4; ++i)
#pragma unroll
    for (int j = 0; j < NF; ++j) acc[i][j] = (f32x4){0.f, 0.f, 0.f, 0.f};

  for (int k0 = 0; k0 < K; k0 += 128) {
#pragma unroll
    for (int u = 0; u < 8; ++u) {
      int lin = u * 256 + tid;
      int r = lin >> 4, c = lin & 15;
      GLD_LDS16(A + (size_t)(m0 + r) * HID + k0 + (c ^ (r & 7)) * 8, &As[lin * 8]);
    }
#pragma unroll
    for (int u = 0; u < BN / 16; ++u) {
      int lin = u * 256 + tid;
      int r = lin >> 4, c = lin & 15;
      GLD_LDS16(B + (size_t)(n0 + r) * HID + k0 + (c ^ (r & 7)) * 8, &Bs[lin * 8]);
    }
    __syncthreads();
#pragma unroll
    for (int kk = 0; kk < 128; kk += 32) {
      s16x8 a[4], b[NF];
#pragma unroll
      for (int i = 0; i < 4; ++i) {
        int row = wm * 64 + i * 16 + col;
        int g = (kk >> 3) + grp;
        a[i] = *(const s16x8*)&As[row * 128 + ((g ^ (row & 7)) * 8)];
      }
#pragma unroll
      for (int j = 0; j < NF; ++j) {
        int row = wn * (BN / 2) + j * 16 + col;
        int g = (kk >> 3) + grp;
        b[j] = *(const s16x8*)&Bs[row * 128 + ((g ^ (row & 7)) * 8)];
      }
#pragma unroll
      for (int i = 0; i < 4; ++i)
#pragma unroll
        for (int j = 0; j < NF; ++j)
          acc[i][j] = MFMA(a[i], b[j], acc[i][j]);
    }
    __syncthreads();
  }

#pragma unroll
  for (int i = 0; i < 4; ++i)
#pragma unroll
    for (int j = 0; j < NF; ++j)
#pragma unroll
      for (int r = 0; r < 4; ++r)
        C[(size_t)(m0 + wm * 64 + i * 16 + grp * 4 + r) * ldc +
          n0 + wn * (BN / 2) + j * 16 + col] = acc[i][j][r];
}

// ---------------- split-K combine (2 partials) + RMSNorm -> bf16 ----------------
__global__ __launch_bounds__(256) void rms_combine2(const float* __restrict__ p,
                                                    unsigned short* __restrict__ out,
                                                    const float* __restrict__ w) {
  int row = blockIdx.x;
  const float* r0 = p + (size_t)row * QL;
  const float* r1 = r0 + 2097152;   // second partial (2048*1024 floats)
  __shared__ float buf[QL];
  __shared__ float red[256];
  float s = 0.f;
  for (int i = threadIdx.x; i < QL; i += 256) {
    float v = r0[i] + r1[i];
    buf[i] = v;
    s += v * v;
  }
  red[threadIdx.x] = s;
  __syncthreads();
  for (int off = 128; off > 0; off >>= 1) {
    if (threadIdx.x < off) red[threadIdx.x] += red[threadIdx.x + off];
    __syncthreads();
  }
  float r = rsqrtf(red[0] / (float)QL + EPS);
  for (int i = threadIdx.x; i < QL; i += 256)
    out[(size_t)row * QL + i] = f2bf(buf[i] * r * w[i]);
}

// ------- split-K combine (4 partials) + KV RMS + RoPE -> kv_bf + kvT -------
// R16: kvT is TILED [S/64][HD][64]. R23: kv split 8->4 (kv_p fits [28M,36M)
// so it can co-live with qa_p + wqb during the merged qakv launch).
__global__ __launch_bounds__(256) void kv_combine4(const float* __restrict__ p,
                                                   const float* __restrict__ w,
                                                   const float* __restrict__ freqs,
                                                   unsigned short* __restrict__ kv,
                                                   unsigned short* __restrict__ kvT) {
  int s = blockIdx.x;
  int d = threadIdx.x;
  const float* b = p + (size_t)s * HD + d;
  float v = 0.f;
#pragma unroll
  for (int z = 0; z < 4; ++z) v += b[(size_t)z * 524288];   // 2048*256 stride
  __shared__ float red[256];
  __shared__ float sm[256];
  red[d] = v * v;
  __syncthreads();
  for (int off = 128; off > 0; off >>= 1) {
    if (d < off) red[d] += red[d + off];
    __syncthreads();
  }
  float r = rsqrtf(red[0] / 256.0f + EPS);
  float nv = v * r * w[d];
  sm[d] = nv;
  __syncthreads();
  float outv = nv;
  if (d >= NOPE) {
    int j = (d - NOPE) >> 1;
    float f = freqs[(size_t)s * (NROT / 2) + j];
    float c = cosf(f), si = sinf(f);
    float x1 = sm[NOPE + 2 * j], x2 = sm[NOPE + 2 * j + 1];
    outv = ((d & 1) == 0) ? (x1 * c - x2 * si) : (x1 * si + x2 * c);
  }
  unsigned short ov = f2bf(outv);
  kv[(size_t)s * HD + d] = ov;
  kvT[(size_t)(s & ~63) * HD + d * 64 + (s & 63)] = ov;   // tiled V^T
}

// ---------------- MFMA flash attention v6 + fused Q-norm/RoPE (R17; FINAL) ----
// 64-key chunks, register prefetch of all global traffic, balanced CU pairing
// (R11), setprio on MFMA clusters (T5), tiled kvT (R16), fused Q RMS+RoPE (R17).
__global__ __launch_bounds__(256, 2) void attn_mfma(
    const unsigned short* __restrict__ qbf,   // (S, NH*HD) bf16 RAW (pre-norm)
    const unsigned short* __restrict__ kvbf,  // (S, HD) bf16
    const unsigned short* __restrict__ kvT,   // tiled [S/64][HD][64] bf16
    const float* __restrict__ sink,
    const float* __restrict__ freqs,
    unsigned short* __restrict__ ob) {        // (S, NH*HD) bf16
  __shared__ __align__(16) unsigned short kv_s[64 * 264];  // [t][d]
  __shared__ __align__(16) unsigned short p_s[64 * 72];    // [row][t] (64 t + 8 pad)
  __shared__ float alpha_s[64];
  __shared__ float inv_s[64];

  const int tid = threadIdx.x;
  const int wave = tid >> 6, lane = tid & 63;
  const int col = lane & 15, grp = lane >> 4;
  // balanced pairing remap: lin in [0,512)
  const int lin = blockIdx.y * gridDim.x + blockIdx.x;
  const int half = lin >> 8, li = lin & 255;
  const int tr = li & 31;
  const int h = (half == 0) ? (li >> 5) : 8 + (li >> 5);
  const int q0 = ((half == 0) ? (31 - tr) : tr) * 64;
  const int qrow = q0 + wave * 16;

  // Q fragments: 8 named s16x8 regs (32 VGPRs)
  const unsigned short* qbase =
      qbf + (size_t)(qrow + col) * (NH * HD) + (size_t)h * HD + grp * 8;
#define QDECL(ko, nam) s16x8 nam = *(const s16x8*)(qbase + (ko) * 32);
  QDECL(0, qf0) QDECL(1, qf1) QDECL(2, qf2) QDECL(3, qf3)
  QDECL(4, qf4) QDECL(5, qf5) QDECL(6, qf6) QDECL(7, qf7)

  // ---- R17 fused Q RMS + RoPE ----
  {
    float sq = 0.f;
#define QSQ(qf) { _Pragma("unroll") \
    for (int j = 0; j < 8; ++j) { float v = bf2f((unsigned short)qf[j]); sq += v * v; } }
    QSQ(qf0) QSQ(qf1) QSQ(qf2) QSQ(qf3) QSQ(qf4) QSQ(qf5) QSQ(qf6) QSQ(qf7)
    sq += __shfl_xor(sq, 16);
    sq += __shfl_xor(sq, 32);
    const float qr_ = rsqrtf(sq * (1.0f / 256.0f) + EPS);
#define QSC(qf) { _Pragma("unroll") \
    for (int j = 0; j < 8; ++j) qf[j] = (short)f2bf(bf2f((unsigned short)qf[j]) * qr_); }
    QSC(qf0) QSC(qf1) QSC(qf2) QSC(qf3) QSC(qf4) QSC(qf5)
    const float* fb = freqs + (size_t)(qrow + col) * (NROT / 2);
#define QSR(qf, jb) { _Pragma("unroll") \
    for (int u = 0; u < 4; ++u) { \
      float f = fb[(jb) + grp * 4 + u]; \
      float c = cosf(f), s = sinf(f); \
      float x1 = bf2f((unsigned short)qf[2 * u]) * qr_; \
      float x2 = bf2f((unsigned short)qf[2 * u + 1]) * qr_; \
      qf[2 * u]     = (short)f2bf(x1 * c - x2 * s); \
      qf[2 * u + 1] = (short)f2bf(x1 * s + x2 * c); } }
    QSR(qf6, 0) QSR(qf7, 16)
  }

  const f32x4 z4 = (f32x4){0.f, 0.f, 0.f, 0.f};
  float m0r = -1e30f, m1r = -1e30f, m2r = -1e30f, m3r = -1e30f;
  float lp0 = 0.f, lp1 = 0.f, lp2 = 0.f, lp3 = 0.f;   // per-lane partial l

#define FOR16(M) M(0,0,o00) M(0,1,o01) M(0,2,o02) M(0,3,o03) \
                 M(1,0,o10) M(1,1,o11) M(1,2,o12) M(1,3,o13) \
                 M(2,0,o20) M(2,1,o21) M(2,2,o22) M(2,3,o23) \
                 M(3,0,o30) M(3,1,o31) M(3,2,o32) M(3,3,o33)
#define DECLO(i, j, onam) f32x4 onam = z4;
  FOR16(DECLO)

  // Staging lane geometry: thread owns rows {tS+8k, k=0..7}, cols [ddS, ddS+8)
  const int tS = tid >> 5, ddS = (tid & 31) * 8;

  // Initial stage of chunk 0
  {
    const unsigned short* sb = kvbf + (size_t)tS * HD + ddS;
#pragma unroll
    for (int k = 0; k < 8; ++k)
      *(s16x8*)&kv_s[(tS + 8 * k) * 264 + ddS] = *(const s16x8*)(sb + (size_t)(8 * k) * HD);
  }

  const int nch = q0 / 64 + 1;
  for (int ch = 0; ch < nch; ++ch) {
    const int t0 = ch * 64;
    __syncthreads();   // kv_s(ch) ready; p_s/alpha_s(ch-1) consumed

    // ---- PREFETCH: next chunk staging (8) + this chunk's vf B-frags (8) ----
    const bool havest = (ch + 1 < nch);
    s16x8 st0 = {}, st1 = {}, st2 = {}, st3 = {}, st4 = {}, st5 = {}, st6 = {}, st7 = {};
    if (havest) {
      const unsigned short* sb = kvbf + (size_t)(t0 + 64 + tS) * HD + ddS;
      st0 = *(const s16x8*)(sb);
      st1 = *(const s16x8*)(sb + 8 * HD);
      st2 = *(const s16x8*)(sb + 16 * HD);
      st3 = *(const s16x8*)(sb + 24 * HD);
      st4 = *(const s16x8*)(sb + 32 * HD);
      st5 = *(const s16x8*)(sb + 40 * HD);
      st6 = *(const s16x8*)(sb + 48 * HD);
      st7 = *(const s16x8*)(sb + 56 * HD);
    }
    // tiled V^T: chunk base = t0*HD, d-row stride 64 elems (128B)
    const unsigned short* vb = kvT + (size_t)t0 * HD + (size_t)(wave * 64 + col) * 64 + grp * 8;
    s16x8 vf00 = *(const s16x8*)(vb);
    s16x8 vf01 = *(const s16x8*)(vb + 32);
    s16x8 vf10 = *(const s16x8*)(vb + 16 * 64);
    s16x8 vf11 = *(const s16x8*)(vb + 16 * 64 + 32);
    s16x8 vf20 = *(const s16x8*)(vb + 32 * 64);
    s16x8 vf21 = *(const s16x8*)(vb + 32 * 64 + 32);
    s16x8 vf30 = *(const s16x8*)(vb + 48 * 64);
    s16x8 vf31 = *(const s16x8*)(vb + 48 * 64 + 32);

    // ---- QK^T: four 16-key tiles ----
    f32x4 sA0 = z4, sA1 = z4, sA2 = z4, sA3 = z4;
    __builtin_amdgcn_s_setprio(1);
#define QKS(ko, qf) { \
      s16x8 b0 = *(const s16x8*)&kv_s[col * 264 + (ko) * 32 + grp * 8]; \
      s16x8 b1 = *(const s16x8*)&kv_s[(16 + col) * 264 + (ko) * 32 + grp * 8]; \
      s16x8 b2 = *(const s16x8*)&kv_s[(32 + col) * 264 + (ko) * 32 + grp * 8]; \
      s16x8 b3 = *(const s16x8*)&kv_s[(48 + col) * 264 + (ko) * 32 + grp * 8]; \
      sA0 = MFMA(qf, b0, sA0); sA1 = MFMA(qf, b1, sA1); \
      sA2 = MFMA(qf, b2, sA2); sA3 = MFMA(qf, b3, sA3); }
    QKS(0, qf0) QKS(1, qf1) QKS(2, qf2) QKS(3, qf3)
    QKS(4, qf4) QKS(5, qf5) QKS(6, qf6) QKS(7, qf7)
    __builtin_amdgcn_s_setprio(0);

    // ---- scale + causal mask ----
#define MASKR(r) { int sg = qrow + grp * 4 + (r); \
    sA0[r] = (t0 + col <= sg)      ? sA0[r] * SCALE : -1e30f; \
    sA1[r] = (t0 + 16 + col <= sg) ? sA1[r] * SCALE : -1e30f; \
    sA2[r] = (t0 + 32 + col <= sg) ? sA2[r] * SCALE : -1e30f; \
    sA3[r] = (t0 + 48 + col <= sg) ? sA3[r] * SCALE : -1e30f; }
    MASKR(0) MASKR(1) MASKR(2) MASKR(3)

    // ---- online softmax: row max -> alpha (l deferred) ----
    float a0, a1, a2, a3;
#define MAXR(r, mr, ar) { \
    float v = fmaxf(fmaxf(sA0[r], sA1[r]), fmaxf(sA2[r], sA3[r])); \
    v = fmaxf(v, __shfl_xor(v, 1)); v = fmaxf(v, __shfl_xor(v, 2)); \
    v = fmaxf(v, __shfl_xor(v, 4)); v = fmaxf(v, __shfl_xor(v, 8)); \
    float mn = fmaxf(mr, v); ar = __expf(mr - mn); mr = mn; }
    MAXR(0, m0r, a0) MAXR(1, m1r, a1) MAXR(2, m2r, a2) MAXR(3, m3r, a3)

    // ---- p, per-lane partial l, p_s writes ----
#define PROW(r, mr, lpr, ar) { \
    float p0 = __expf(sA0[r] - mr); float p1 = __expf(sA1[r] - mr); \
    float p2 = __expf(sA2[r] - mr); float p3 = __expf(sA3[r] - mr); \
    lpr = lpr * ar + (p0 + p1) + (p2 + p3); \
    int prow = (wave * 16 + grp * 4 + (r)) * 72; \
    p_s[prow + col] = f2bf(p0);      p_s[prow + 16 + col] = f2bf(p1); \
    p_s[prow + 32 + col] = f2bf(p2); p_s[prow + 48 + col] = f2bf(p3); }
    PROW(0, m0r, lp0, a0) PROW(1, m1r, lp1, a1) PROW(2, m2r, lp2, a2) PROW(3, m3r, lp3, a3)

    if (col == 0) {
      alpha_s[wave * 16 + grp * 4 + 0] = a0;
      alpha_s[wave * 16 + grp * 4 + 1] = a1;
      alpha_s[wave * 16 + grp * 4 + 2] = a2;
      alpha_s[wave * 16 + grp * 4 + 3] = a3;
    }
    __syncthreads();   // p_s/alpha_s ready; kv_s(ch) reads complete

    // ---- commit prefetched next chunk into kv_s ----
    if (havest) {
      *(s16x8*)&kv_s[tS * 264 + ddS]        = st0;
      *(s16x8*)&kv_s[(tS + 8) * 264 + ddS]  = st1;
      *(s16x8*)&kv_s[(tS + 16) * 264 + ddS] = st2;
      *(s16x8*)&kv_s[(tS + 24) * 264 + ddS] = st3;
      *(s16x8*)&kv_s[(tS + 32) * 264 + ddS] = st4;
      *(s16x8*)&kv_s[(tS + 40) * 264 + ddS] = st5;
      *(s16x8*)&kv_s[(tS + 48) * 264 + ddS] = st6;
      *(s16x8*)&kv_s[(tS + 56) * 264 + ddS] = st7;
    }

    // ---- rescale o-accs (alpha broadcast from LDS) ----
#define RESC(i) { f32x4 av = (f32x4){alpha_s[(i)*16 + grp*4 + 0], alpha_s[(i)*16 + grp*4 + 1], \
                                     alpha_s[(i)*16 + grp*4 + 2], alpha_s[(i)*16 + grp*4 + 3]}; \
    o##i##0 *= av; o##i##1 *= av; o##i##2 *= av; o##i##3 *= av; }
    RESC(0) RESC(1) RESC(2) RESC(3)

    // ---- PV: d-partition, K=64 in two halves, vf from prefetched regs ----
    s16x8 pf00 = *(const s16x8*)&p_s[(0 * 16 + col) * 72 + grp * 8];
    s16x8 pf01 = *(const s16x8*)&p_s[(0 * 16 + col) * 72 + 32 + grp * 8];
    s16x8 pf10 = *(const s16x8*)&p_s[(1 * 16 + col) * 72 + grp * 8];
    s16x8 pf11 = *(const s16x8*)&p_s[(1 * 16 + col) * 72 + 32 + grp * 8];
    s16x8 pf20 = *(const s16x8*)&p_s[(2 * 16 + col) * 72 + grp * 8];
    s16x8 pf21 = *(const s16x8*)&p_s[(2 * 16 + col) * 72 + 32 + grp * 8];
    s16x8 pf30 = *(const s16x8*)&p_s[(3 * 16 + col) * 72 + grp * 8];
    s16x8 pf31 = *(const s16x8*)&p_s[(3 * 16 + col) * 72 + 32 + grp * 8];
    __builtin_amdgcn_s_setprio(1);
#define PVJ(j) { \
      o0##j = MFMA(pf00, vf##j##0, o0##j); o0##j = MFMA(pf01, vf##j##1, o0##j); \
      o1##j = MFMA(pf10, vf##j##0, o1##j); o1##j = MFMA(pf11, vf##j##1, o1##j); \
      o2##j = MFMA(pf20, vf##j##0, o2##j); o2##j = MFMA(pf21, vf##j##1, o2##j); \
      o3##j = MFMA(pf30, vf##j##0, o3##j); o3##j = MFMA(pf31, vf##j##1, o3##j); }
    PVJ(0) PVJ(1) PVJ(2) PVJ(3)
    __builtin_amdgcn_s_setprio(0);
  }

  // ---- final l reduction + inv broadcast ----
  const float sk = sink[h];
  {
#define LRED(lpr) { lpr += __shfl_xor(lpr, 1); lpr += __shfl_xor(lpr, 2); \
                    lpr += __shfl_xor(lpr, 4); lpr += __shfl_xor(lpr, 8); }
    LRED(lp0) LRED(lp1) LRED(lp2) LRED(lp3)
    float i0 = 1.f / (lp0 + __expf(sk - m0r));
    float i1 = 1.f / (lp1 + __expf(sk - m1r));
    float i2 = 1.f / (lp2 + __expf(sk - m2r));
    float i3 = 1.f / (lp3 + __expf(sk - m3r));
    if (col == 0) {
      inv_s[wave * 16 + grp * 4 + 0] = i0;
      inv_s[wave * 16 + grp * 4 + 1] = i1;
      inv_s[wave * 16 + grp * 4 + 2] = i2;
      inv_s[wave * 16 + grp * 4 + 3] = i3;
    }
  }
  __syncthreads();

  // ---- epilogue: normalize, conj-RoPE (wave 3 owns dims 192..255), store ----
#define EPIJ(i, j, onam, ivv) { \
    float v0 = onam[0] * ivv[0]; float v1 = onam[1] * ivv[1]; \
    float v2 = onam[2] * ivv[2]; float v3 = onam[3] * ivv[3]; \
    if (wave == 3) { \
      int jr = ((j) * 16 + col) >> 1; \
      float f0 = freqs[(size_t)(q0 + (i) * 16 + grp * 4 + 0) * 32 + jr]; \
      float f1 = freqs[(size_t)(q0 + (i) * 16 + grp * 4 + 1) * 32 + jr]; \
      float f2 = freqs[(size_t)(q0 + (i) * 16 + grp * 4 + 2) * 32 + jr]; \
      float f3 = freqs[(size_t)(q0 + (i) * 16 + grp * 4 + 3) * 32 + jr]; \
      float p0 = __shfl_xor(v0, 1), p1 = __shfl_xor(v1, 1); \
      float p2 = __shfl_xor(v2, 1), p3 = __shfl_xor(v3, 1); \
      v0 = (col & 1) ? (v0 * cosf(f0) - p0 * sinf(f0)) : (v0 * cosf(f0) + p0 * sinf(f0)); \
      v1 = (col & 1) ? (v1 * cosf(f1) - p1 * sinf(f1)) : (v1 * cosf(f1) + p1 * sinf(f1)); \
      v2 = (col & 1) ? (v2 * cosf(f2) - p2 * sinf(f2)) : (v2 * cosf(f2) + p2 * sinf(f2)); \
      v3 = (col & 1) ? (v3 * cosf(f3) - p3 * sinf(f3)) : (v3 * cosf(f3) + p3 * sinf(f3)); \
    } \
    size_t obase = (size_t)(q0 + (i) * 16 + grp * 4) * (NH * HD) + (size_t)h * HD + \
                   wave * 64 + (j) * 16 + col; \
    ob[obase] = f2bf(v0); ob[obase + (NH * HD)] = f2bf(v1); \
    ob[obase + 2 * (NH * HD)] = f2bf(v2); ob[obase + 3 * (NH * HD)] = f2bf(v3); }
#define EPII(i) { \
    f32x4 ivv = (f32x4){inv_s[(i)*16 + grp*4 + 0], inv_s[(i)*16 + grp*4 + 1], \
                        inv_s[(i)*16 + grp*4 + 2], inv_s[(i)*16 + grp*4 + 3]}; \
    EPIJ(i, 0, o##i##0, ivv) EPIJ(i, 1, o##i##1, ivv) \
    EPIJ(i, 2, o##i##2, ivv) EPIJ(i, 3, o##i##3, ivv) }
  EPII(0) EPII(1) EPII(2) EPII(3)
}

extern "C" void kernel_launch(void* const* d_in, const int* in_sizes, int n_in,
                              void* d_out, int out_size, void* d_ws, size_t ws_size,
                              hipStream_t stream) {
  const float* x         = (const float*)d_in[0];
  const float* freqs     = (const float*)d_in[1];
  const float* wq_a      = (const float*)d_in[2];
  const float* q_norm_w  = (const float*)d_in[3];
  const float* wq_b      = (const float*)d_in[4];
  const float* wkv       = (const float*)d_in[5];
  const float* kv_norm_w = (const float*)d_in[6];
  const float* wo_a_w    = (const float*)d_in[7];
  const float* wo_b      = (const float*)d_in[8];
  const float* sink      = (const float*)d_in[9];
  float* out = (float*)d_out;

  // Workspace (byte offsets, 55 MB total):
  //  [0,4M)    qa_bf
  //  [4M,20M)  qa fp32 partials (qakv z<2, 2x8MB) -> then q_bf (g3 out).
  //            After attn: orb_bf [4M,12M), wob_bf [12M,20M)
  //  [20M,36M) o_bf (attn out); x_bf [20M,28M) dead before attn writes;
  //            kv fp32 partials [28M,36M) (qakv z>=2, 4x2MB) consumed by
  //            kv_combine4 before attn writes o_bf.
  //  [36M,40M) wqa_bf  [40M,48M) wqb_bf  [48M,49M) wkv_bf
  //  [49M,53M) woa_bf  [53M,54M) kv_bf  [54M,55M) kvT_bf
  char* ws = (char*)d_ws;
  const size_t MB = 1024 * 1024;
  unsigned short* qa_bf   = (unsigned short*)(ws + 0 * MB);
  float*          qa_p    = (float*)(ws + 4 * MB);
  unsigned short* q_bf    = (unsigned short*)(ws + 4 * MB);
  unsigned short* orb_bf  = (unsigned short*)(ws + 4 * MB);
  unsigned short* wob_bf  = (unsigned short*)(ws + 12 * MB);
  unsigned short* o_bf    = (unsigned short*)(ws + 20 * MB);
  unsigned short* x_bf    = (unsigned short*)(ws + 20 * MB);
  float*          kv_p    = (float*)(ws + 28 * MB);
  unsigned short* wqa_bf  = (unsigned short*)(ws + 36 * MB);
  unsigned short* wqb_bf  = (unsigned short*)(ws + 40 * MB);
  unsigned short* wkv_bf  = (unsigned short*)(ws + 48 * MB);
  unsigned short* woa_bf  = (unsigned short*)(ws + 49 * MB);
  unsigned short* kv_bf   = (unsigned short*)(ws + 53 * MB);
  unsigned short* kvT_bf  = (unsigned short*)(ws + 54 * MB);

  dim3 blk(256);

  // 0) fused fp32 -> bf16 conversion of the 5 pre-attention tensors
  conv5<<<dim3(12800), blk, 0, stream>>>(x, wq_a, wq_b, wkv, wo_a_w,
                                         x_bf, wqa_bf, wqb_bf, wkv_bf, woa_bf);

  // 1) MERGED qa (split-K x2) + kv (split-K x4) partials -> fp32 (R23)
  gemm_qakv<<<dim3(QL / 64, S_LEN / 128, 6), blk, 0, stream>>>(
      x_bf, wqa_bf, wkv_bf, qa_p, kv_p);
  // 2) combine + RMS -> qa_bf
  rms_combine2<<<dim3(S_LEN), blk, 0, stream>>>(qa_p, qa_bf, q_norm_w);
  // 3) combine + RMS + RoPE -> kv_bf + kvT (tiled)
  kv_combine4<<<dim3(S_LEN), blk, 0, stream>>>(kv_p, kv_norm_w, freqs, kv_bf, kvT_bf);
  // 4) q = qa @ wq_b^T  (2048x4096, K=1024) -> bf16 RAW (norm fused into attn)
  gemm_bf16<128><<<dim3(NH * HD / 128, S_LEN / 128, 1), blk, 0, stream>>>(
      qa_bf, wqb_bf, q_bf, QL, QL, QL, NH * HD, 0, 0, 0, 1);
  // 5) flash attention (Q-norm/RoPE fused) -> o_bf
  attn_mfma<<<dim3(S_LEN / 64, NH), blk, 0, stream>>>(q_bf, kv_bf, kvT_bf, sink, freqs, o_bf);
  // 5b) convert wo_b into [12M,20M) — q_bf dead after attention
  f32_to_bf16<<<dim3(4096), blk, 0, stream>>>(wo_b, wob_bf, 4 * 1024 * 1024 / 4);
  // 6) grouped projection via z-grid, BN=64 (grid 512 blocks)
  gemm_bf16<64><<<dim3(OR_ / 64, S_LEN / 128, NG), blk, 0, stream>>>(
      o_bf, woa_bf, orb_bf, HPG * HD, NH * HD, HPG * HD, NG * OR_,
      (long)(HPG * HD), (long)OR_ * (HPG * HD), (long)OR_, 1);
  // 7) out = orb @ wo_b^T (2048x2048, K=2048) -> fp32, BN=64 (512 blocks)
  gemm_bf16<64><<<dim3(HID / 64, S_LEN / 128, 1), blk, 0, stream>>>(
      orb_bf, wob_bf, out, NG * OR_, NG * OR_, NG * OR_, HID, 0, 0, 0, 0);
}